// Round 7
// baseline (937.141 us; speedup 1.0000x reference)
//
#include <hip/hip_runtime.h>
#include <math.h>

#define S 256
#define D 512
#define P 16
#define NIJ (D*D)
#define CCAP 1024   // per-(pos,chunk) candidate stash capacity

__device__ __forceinline__ float gelu_f(float x){ return 0.5f*x*(1.f+erff(x*0.70710678118654752f)); }
__device__ __forceinline__ float silu_f(float x){ return x/(1.f+expf(-x)); }
__device__ __forceinline__ float sigm_f(float x){ return 1.f/(1.f+expf(-x)); }

// K1: LayerNorm + RoPE per row
__global__ void __launch_bounds__(256) k_ln_rope(const float* __restrict__ x,
    const float* __restrict__ g, const float* __restrict__ b,
    float* __restrict__ xn, float* __restrict__ xr){
  int s2 = blockIdx.x, tid = threadIdx.x;
  __shared__ float red[256];
  __shared__ float xnl[512];
  const float* xrow = x + s2*D;
  float v0 = xrow[tid], v1 = xrow[tid+256];
  red[tid] = v0+v1; __syncthreads();
  for (int st=128; st>0; st>>=1){ if (tid<st) red[tid]+=red[tid+st]; __syncthreads(); }
  float mean = red[0]*(1.f/512.f); __syncthreads();
  float d0=v0-mean, d1=v1-mean;
  red[tid]=d0*d0+d1*d1; __syncthreads();
  for (int st=128; st>0; st>>=1){ if (tid<st) red[tid]+=red[tid+st]; __syncthreads(); }
  float var = red[0]*(1.f/512.f);
  float rstd = rsqrtf(var+1e-5f);
  float a0 = d0*rstd*g[tid]+b[tid];
  float a1 = d1*rstd*g[tid+256]+b[tid+256];
  xn[s2*D+tid]=a0; xn[s2*D+tid+256]=a1;
  xnl[tid]=a0; xnl[tid+256]=a1;
  __syncthreads();
  int j = tid;
  float e = (float)(2*j)*(1.f/512.f);
  float inv = 1.f/powf(10000.f, e);
  float ang = (float)s2 * inv;
  float c = cosf(ang), sn = sinf(ang);
  float p0 = xnl[2*j], p1 = xnl[2*j+1];
  xr[s2*D+2*j]   = p0*c - p1*sn;
  xr[s2*D+2*j+1] = p1*c + p0*sn;
}

// K2: column means
__global__ void __launch_bounds__(256) k_colmean(const float* __restrict__ xr,
    const float* __restrict__ bank, float* __restrict__ meanxr, float* __restrict__ memmean){
  int tid=threadIdx.x;
  if (blockIdx.x<2){
    int d2 = blockIdx.x*256+tid; float acc=0.f;
    for (int s2=0;s2<S;++s2) acc += xr[s2*D+d2];
    meanxr[d2]=acc*(1.f/256.f);
  } else {
    int d2=(blockIdx.x-2)*256+tid; float acc=0.f;
    for (int r=0;r<512;++r) acc += bank[r*D+d2];
    memmean[d2]=acc*(1.f/512.f);
  }
}

// K3: window MLP -> kk; fold ctx/mem halves into effective biases
__global__ void __launch_bounds__(256) k_head(const float* __restrict__ meanxr, const float* __restrict__ memmean,
    const float* __restrict__ ww1, const float* __restrict__ wb1,
    const float* __restrict__ ww2, const float* __restrict__ wb2,
    const float* __restrict__ sw1, const float* __restrict__ sb1,
    const float* __restrict__ iw1, const float* __restrict__ ib1,
    const float* __restrict__ mw1, const float* __restrict__ mb1,
    float* __restrict__ ctxsel, float* __restrict__ ctxint,
    float* __restrict__ mempart, int* __restrict__ kkout){
  int tid=threadIdx.x;
  __shared__ float mx[512], mm[512], gw[64];
  mx[tid]=meanxr[tid]; mx[tid+256]=meanxr[tid+256];
  mm[tid]=memmean[tid]; mm[tid+256]=memmean[tid+256];
  __syncthreads();
  if (tid<64){ float a=wb1[tid]; for (int d2=0;d2<512;++d2) a=fmaf(mx[d2], ww1[d2*64+tid], a); gw[tid]=gelu_f(a); }
  __syncthreads();
  if (tid==0){
    float a=wb2[0]; for (int h=0;h<64;++h) a=fmaf(gw[h], ww2[h], a);
    float win = sigm_f(a)*3840.f+256.f;
    float asp = 0.1f*(win*(1.f/4096.f));
    float t = 262144.f*asp;
    int kk=(int)t; if (kk<1) kk=1;
    *kkout=kk;
  }
  if (tid<32){ float a=sb1[tid]; for (int d2=0;d2<512;++d2) a=fmaf(mx[d2], sw1[(512+d2)*32+tid], a); ctxsel[tid]=a; }
  if (tid>=64 && tid<128){ int o=tid-64; float a=ib1[o]; for (int d2=0;d2<512;++d2) a=fmaf(mx[d2], iw1[(512+d2)*64+o], a); ctxint[o]=a; }
  for (int o=tid;o<512;o+=256){ float a=mb1[o]; for (int d2=0;d2<512;++d2) a=fmaf(mm[d2], mw1[(512+d2)*512+o], a); mempart[o]=a; }
}

// K4: per-position selection MLP (softmax pw) + intensity
__global__ void __launch_bounds__(256) k_selint(const float* __restrict__ xr,
    const float* __restrict__ ctxsel, const float* __restrict__ ctxint,
    const float* __restrict__ sw1, const float* __restrict__ sw2, const float* __restrict__ sb2,
    const float* __restrict__ iw1, const float* __restrict__ iw2, const float* __restrict__ ib2,
    float* __restrict__ pw, float* __restrict__ inten){
  int s2=blockIdx.x, tid=threadIdx.x;
  __shared__ float xl[512]; __shared__ float h1[32], h2[64], lg[16];
  xl[tid]=xr[s2*D+tid]; xl[tid+256]=xr[s2*D+tid+256];
  __syncthreads();
  if (tid<32){ float a=ctxsel[tid]; for (int d2=0;d2<512;++d2) a=fmaf(xl[d2], sw1[d2*32+tid], a); h1[tid]=gelu_f(a); }
  else if (tid<96){ int o=tid-32; float a=ctxint[o]; for (int d2=0;d2<512;++d2) a=fmaf(xl[d2], iw1[d2*64+o], a); h2[o]=gelu_f(a); }
  __syncthreads();
  if (tid<16){ float a=sb2[tid]; for (int h=0;h<32;++h) a=fmaf(h1[h], sw2[h*16+tid], a); lg[tid]=a; }
  __syncthreads();
  if (tid==0){
    float m=lg[0]; for (int p2=1;p2<16;++p2) m=fmaxf(m,lg[p2]);
    float sm=0.f; float e[16];
    for (int p2=0;p2<16;++p2){ e[p2]=expf(lg[p2]-m); sm+=e[p2]; }
    float r=1.f/sm;
    for (int p2=0;p2<16;++p2) pw[s2*16+p2]=e[p2]*r;
  }
  if (tid==64){ float a=ib2[0]; for (int h=0;h<64;++h) a=fmaf(h2[h], iw2[h], a); inten[s2]=sigm_f(a); }
}

// K5a: shared-sweep histogram. grid (64 pos-groups, 4 chunks); 4 positions/block.
// 13-bit bins (abs bits >> 18). Two 8-pattern halves keep live VGPR ~70.
__global__ void __launch_bounds__(1024,4) k_fhist(const float* __restrict__ pat,
    const float* __restrict__ pw, unsigned* __restrict__ ghist){
  __shared__ unsigned hist[4*8192];
  __shared__ float pws4[64];
  int g=blockIdx.x, c=blockIdx.y, tid=threadIdx.x;
  if (tid<64) pws4[tid]=pw[g*64+tid];
  for (int i=tid;i<32768;i+=1024) hist[i]=0u;
  __syncthreads();
  const float4* patv=(const float4*)pat;
  int base=c*16384;
  for (int it=0;it<16;++it){
    int f4=base+(it<<10)+tid;
    float4 acc[4];
    #pragma unroll
    for (int pp=0;pp<4;++pp) acc[pp]=make_float4(0.f,0.f,0.f,0.f);
    #pragma unroll
    for (int h=0;h<2;++h){
      float4 pv[8];
      #pragma unroll
      for (int p=0;p<8;++p) pv[p]=patv[(((h<<3)+p)<<16)+f4];
      #pragma unroll
      for (int pp=0;pp<4;++pp){
        #pragma unroll
        for (int p=0;p<8;++p){
          float w=pws4[(pp<<4)+(h<<3)+p];
          acc[pp].x=fmaf(w,pv[p].x,acc[pp].x); acc[pp].y=fmaf(w,pv[p].y,acc[pp].y);
          acc[pp].z=fmaf(w,pv[p].z,acc[pp].z); acc[pp].w=fmaf(w,pv[p].w,acc[pp].w);
        }
      }
    }
    #pragma unroll
    for (int pp=0;pp<4;++pp){
      unsigned* h2=&hist[pp<<13];
      atomicAdd(&h2[(__float_as_uint(acc[pp].x)&0x7fffffffu)>>18],1u);
      atomicAdd(&h2[(__float_as_uint(acc[pp].y)&0x7fffffffu)>>18],1u);
      atomicAdd(&h2[(__float_as_uint(acc[pp].z)&0x7fffffffu)>>18],1u);
      atomicAdd(&h2[(__float_as_uint(acc[pp].w)&0x7fffffffu)>>18],1u);
    }
  }
  __syncthreads();
  for (int i=tid;i<32768;i+=1024){
    unsigned v=hist[i];
    if (v) atomicAdd(&ghist[(((g<<2)+(i>>13))<<13)+(i&8191)], v);
  }
}

// K5b: per-position threshold bin from 8192-bin global histogram.
__global__ void __launch_bounds__(256) k_fth(const unsigned* __restrict__ ghist,
    const int* __restrict__ kkin, unsigned* __restrict__ meta){
  int pos=blockIdx.x, tid=threadIdx.x;
  __shared__ unsigned part[256]; __shared__ unsigned sup[16];
  const unsigned* h=ghist+(pos<<13);
  unsigned s=0;
  for (int k=0;k<32;++k) s+=h[tid*32+k];
  part[tid]=s; __syncthreads();
  if (tid<16){ unsigned t=0; for (int k=0;k<16;++k) t+=part[tid*16+k]; sup[tid]=t; }
  __syncthreads();
  if (tid==0){
    unsigned kk=(unsigned)(*kkin);
    unsigned cum=0; int u=0;
    for (int j=15;j>=0;--j){ if (cum+sup[j]>=kk){ u=j; break; } cum+=sup[j]; }
    int t=u*16;
    for (int j=u*16+15;j>=u*16;--j){ if (cum+part[j]>=kk){ t=j; break; } cum+=part[j]; }
    int b=t*32;
    for (int j=t*32+31;j>=t*32;--j){ if (cum+h[j]>=kk){ b=j; break; } cum+=h[j]; }
    meta[pos*4+0]=(unsigned)b; meta[pos*4+1]=kk-cum; meta[pos*4+2]=h[b];
  }
}

// K5c: shared-sweep masked matvec. grid (32 pos-groups, 8 chunks); 8 pos/block.
// Wave-level shuffle reduce (all 64 lanes of a wave are in the same output row).
// Per-(pos,chunk) exclusive stash regions -> plain stores, no global atomics.
__global__ void __launch_bounds__(1024,4) k_fmv(const float* __restrict__ pat,
    const float* __restrict__ pw, const float* __restrict__ xn,
    const unsigned* __restrict__ meta, float* __restrict__ goutr, float* __restrict__ goutrb,
    unsigned* __restrict__ gbits, float* __restrict__ gcon,
    unsigned short* __restrict__ grow, unsigned* __restrict__ gcount, unsigned* __restrict__ gofl){
  __shared__ float pws8[128];
  __shared__ float xnl[4096];
  __shared__ float outr[512];   // 8 pos x 64 rows (this chunk's rows)
  __shared__ float outrb[512];  // bin-sum per row (fallback path)
  __shared__ unsigned lcnt[8];
  int g=blockIdx.x, c=blockIdx.y, tid=threadIdx.x;
  if (tid<128) pws8[tid]=pw[g*128+tid];
  for (int i=tid;i<4096;i+=1024) xnl[i]=xn[(g<<12)+i];
  if (tid<512){ outr[tid]=0.f; outrb[tid]=0.f; }
  if (tid<8) lcnt[tid]=0u;
  __syncthreads();
  unsigned bst[8];
  #pragma unroll
  for (int pp=0;pp<8;++pp) bst[pp]=meta[((g<<3)+pp)*4];
  const float4* patv=(const float4*)pat;
  int lane=tid&63;
  for (int it=0;it<8;++it){
    int f4=(c<<13)+(it<<10)+tid;
    int rowg=f4>>7;             // global row 0..511
    int row=rowg&63;            // local row in this chunk
    int col0=(f4&127)<<2;
    float4 fl[8];
    #pragma unroll
    for (int pp=0;pp<8;++pp) fl[pp]=make_float4(0.f,0.f,0.f,0.f);
    #pragma unroll
    for (int h=0;h<2;++h){
      float4 pv[8];
      #pragma unroll
      for (int p=0;p<8;++p) pv[p]=patv[(((h<<3)+p)<<16)+f4];
      #pragma unroll
      for (int pp=0;pp<8;++pp){
        #pragma unroll
        for (int p=0;p<8;++p){
          float w=pws8[(pp<<4)+(h<<3)+p];
          fl[pp].x=fmaf(w,pv[p].x,fl[pp].x); fl[pp].y=fmaf(w,pv[p].y,fl[pp].y);
          fl[pp].z=fmaf(w,pv[p].z,fl[pp].z); fl[pp].w=fmaf(w,pv[p].w,fl[pp].w);
        }
      }
    }
    #pragma unroll
    for (int pp=0;pp<8;++pp){
      float4 xq=*(const float4*)&xnl[(pp<<9)+col0];
      float vv[4]={fl[pp].x,fl[pp].y,fl[pp].z,fl[pp].w};
      float xv[4]={xq.x,xq.y,xq.z,xq.w};
      float lacc=0.f, lb=0.f;
      #pragma unroll
      for (int q=0;q<4;++q){
        unsigned bits=__float_as_uint(vv[q])&0x7fffffffu;
        unsigned pfx=bits>>18;
        if (pfx>bst[pp]) lacc=fmaf(vv[q],xv[q],lacc);
        else if (pfx==bst[pp]){
          float con=vv[q]*xv[q];
          lb+=con;
          unsigned idx=atomicAdd(&lcnt[pp],1u);
          if (idx<CCAP){
            int o=((((g<<3)+pp)<<3)+c)*CCAP+idx;
            gbits[o]=bits; gcon[o]=con; grow[o]=(unsigned short)rowg;
          }
        }
      }
      #pragma unroll
      for (int m=32;m>0;m>>=1){ lacc+=__shfl_xor(lacc,m,64); lb+=__shfl_xor(lb,m,64); }
      if (lane==0){
        if (lacc!=0.f) atomicAdd(&outr[(pp<<6)+row], lacc);
        if (lb!=0.f)   atomicAdd(&outrb[(pp<<6)+row], lb);
      }
    }
  }
  __syncthreads();
  if (tid<512){
    int pp=tid>>6, r=tid&63;
    goutr [((g<<3)+pp)*512+(c<<6)+r]=outr[tid];
    goutrb[((g<<3)+pp)*512+(c<<6)+r]=outrb[tid];
  }
  if (tid<8){
    unsigned n=lcnt[tid];
    gcount[((g<<3)+tid)*8+c]=n;
    if (n>CCAP) gofl[(g<<3)+tid]=1u;
  }
}

// K5d: per-position exact refinement over stashed candidates + apply + residual + LN2.
__global__ void __launch_bounds__(256) k_fref(const float* __restrict__ x,
    const float* __restrict__ goutr, const float* __restrict__ goutrb,
    const unsigned* __restrict__ meta, const unsigned* __restrict__ gcount,
    const unsigned* __restrict__ gofl, const unsigned* __restrict__ gbits,
    const float* __restrict__ gcon, const unsigned short* __restrict__ grow,
    const float* __restrict__ inten, const float* __restrict__ n2g, const float* __restrict__ n2b,
    float* __restrict__ co){
  int pos=blockIdx.x, tid=threadIdx.x;
  __shared__ float outr[512]; __shared__ unsigned rhist[2048]; __shared__ unsigned rpart[128];
  __shared__ unsigned thsh[4]; __shared__ float red[256];
  outr[tid]=goutr[pos*512+tid]; outr[tid+256]=goutr[pos*512+tid+256];
  unsigned bstar=meta[pos*4], rnk=meta[pos*4+1];
  bool ofl = gofl[pos]!=0u;
  if (ofl){
    // fallback: include whole threshold bin (precomputed per-row bin sums)
    outr[tid]+=goutrb[pos*512+tid]; outr[tid+256]+=goutrb[pos*512+tid+256];
    __syncthreads();
  } else {
    for (int i=tid;i<2048;i+=256) rhist[i]=0u;
    __syncthreads();
    for (int c=0;c<8;++c){
      unsigned n=gcount[pos*8+c]; if (n>CCAP) n=CCAP;
      const unsigned* cb=gbits+(((pos<<3)+c)*CCAP);
      for (unsigned i=tid;i<n;i+=256) atomicAdd(&rhist[(cb[i]>>7)&0x7ffu],1u);
    }
    __syncthreads();
    if (tid<128){ unsigned t=0;
      #pragma unroll
      for (int k=0;k<16;++k) t+=rhist[tid*16+k];
      rpart[tid]=t; }
    __syncthreads();
    if (tid==0){
      unsigned cum=0; int rp=0;
      for (int j=127;j>=0;--j){ if (cum+rpart[j]>=rnk){ rp=j; break; } cum+=rpart[j]; }
      int sub=rp*16;
      for (int j=rp*16+15;j>=rp*16;--j){ if (cum+rhist[j]>=rnk){ sub=j; break; } cum+=rhist[j]; }
      thsh[0]=(unsigned)sub; thsh[1]=rnk-cum;
    }
    __syncthreads();
    unsigned sub=thsh[0], r2=thsh[1];
    if (tid<128) rhist[tid]=0u;
    __syncthreads();
    for (int c=0;c<8;++c){
      unsigned n=gcount[pos*8+c]; if (n>CCAP) n=CCAP;
      const unsigned* cb=gbits+(((pos<<3)+c)*CCAP);
      for (unsigned i=tid;i<n;i+=256) if (((cb[i]>>7)&0x7ffu)==sub) atomicAdd(&rhist[cb[i]&127u],1u);
    }
    __syncthreads();
    if (tid==0){
      unsigned cum=0; unsigned lo=0;
      for (int j=127;j>=0;--j){ if (cum+rhist[j]>=r2){ lo=(unsigned)j; break; } cum+=rhist[j]; }
      thsh[2]=(bstar<<18)|(sub<<7)|lo;
    }
    __syncthreads();
    unsigned thb=thsh[2];
    for (int c=0;c<8;++c){
      unsigned n=gcount[pos*8+c]; if (n>CCAP) n=CCAP;
      int base=((pos<<3)+c)*CCAP;
      for (unsigned i=tid;i<n;i+=256)
        if (gbits[base+i]>=thb) atomicAdd(&outr[grow[base+i]], gcon[base+i]);
    }
  }
  __syncthreads();
  float it=inten[pos];
  float t0=x[pos*D+tid]+outr[tid]*it;
  float t1=x[pos*D+tid+256]+outr[tid+256]*it;
  red[tid]=t0+t1; __syncthreads();
  for (int st=128;st>0;st>>=1){ if (tid<st) red[tid]+=red[tid+st]; __syncthreads(); }
  float mean=red[0]*(1.f/512.f); __syncthreads();
  float d0=t0-mean, d1=t1-mean;
  red[tid]=d0*d0+d1*d1; __syncthreads();
  for (int st=128;st>0;st>>=1){ if (tid<st) red[tid]+=red[tid+st]; __syncthreads(); }
  float var=red[0]*(1.f/512.f);
  float rstd=rsqrtf(var+1e-5f);
  co[pos*D+tid]=d0*rstd*n2g[tid]+n2b[tid];
  co[pos*D+tid+256]=d1*rstd*n2g[tid+256]+n2b[tid+256];
}

// ---------------- GEMM: RTx64 tile, LDS-staged, prefetch ----------------
template<int ACT, int RES, int RT>
__global__ void __launch_bounds__(256) k_gemm2(const float* __restrict__ A, const float* __restrict__ W,
    const float* __restrict__ bias, const float* __restrict__ res,
    float* __restrict__ C, int K, int N){
  __shared__ float Ast[32][RT+4];
  __shared__ float Ws[32][68];
  const int RPT=RT/8;
  int tid=threadIdx.x;
  int cb=blockIdx.x<<6;
  int s0=blockIdx.y*RT;
  int rid=tid>>5;
  int cid=tid&31;
  int arow=tid>>3, akq=tid&7;
  int wrow=tid>>4, wc4=tid&15;
  bool aload = tid < RT*8;
  float acc[RPT][2];
  #pragma unroll
  for (int r=0;r<RPT;++r){ acc[r][0]=0.f; acc[r][1]=0.f; }
  const float* Aptr = A + (size_t)(s0+arow)*K + (akq<<2);
  const float* Wptr0 = W + (size_t)wrow*N + cb + (wc4<<2);
  const float* Wptr1 = W + (size_t)(wrow+16)*N + cb + (wc4<<2);
  float4 av=make_float4(0.f,0.f,0.f,0.f);
  if (aload) av=*(const float4*)Aptr;
  float4 w0=*(const float4*)Wptr0;
  float4 w1=*(const float4*)Wptr1;
  for (int k0=0;k0<K;k0+=32){
    if (aload){
      Ast[(akq<<2)+0][arow]=av.x; Ast[(akq<<2)+1][arow]=av.y;
      Ast[(akq<<2)+2][arow]=av.z; Ast[(akq<<2)+3][arow]=av.w;
    }
    *(float4*)&Ws[wrow][wc4<<2]=w0;
    *(float4*)&Ws[wrow+16][wc4<<2]=w1;
    __syncthreads();
    if (k0+32<K){
      if (aload) av=*(const float4*)(Aptr + k0+32);
      w0=*(const float4*)(Wptr0 + (size_t)(k0+32)*N);
      w1=*(const float4*)(Wptr1 + (size_t)(k0+32)*N);
    }
    #pragma unroll
    for (int kk=0;kk<32;++kk){
      float b0=Ws[kk][cid], b1=Ws[kk][cid+32];
      if constexpr (RPT==4){
        float4 a4=*(const float4*)&Ast[kk][rid<<2];
        acc[0][0]=fmaf(a4.x,b0,acc[0][0]); acc[0][1]=fmaf(a4.x,b1,acc[0][1]);
        acc[1][0]=fmaf(a4.y,b0,acc[1][0]); acc[1][1]=fmaf(a4.y,b1,acc[1][1]);
        acc[2][0]=fmaf(a4.z,b0,acc[2][0]); acc[2][1]=fmaf(a4.z,b1,acc[2][1]);
        acc[3][0]=fmaf(a4.w,b0,acc[3][0]); acc[3][1]=fmaf(a4.w,b1,acc[3][1]);
      } else {
        float2 a2=*(const float2*)&Ast[kk][rid<<1];
        acc[0][0]=fmaf(a2.x,b0,acc[0][0]); acc[0][1]=fmaf(a2.x,b1,acc[0][1]);
        acc[1][0]=fmaf(a2.y,b0,acc[1][0]); acc[1][1]=fmaf(a2.y,b1,acc[1][1]);
      }
    }
    __syncthreads();
  }
  float bb0=bias[cb+cid], bb1=bias[cb+cid+32];
  #pragma unroll
  for (int r=0;r<RPT;++r){
    int row=s0+rid*RPT+r;
    #pragma unroll
    for (int c=0;c<2;++c){
      int col=cb+cid+(c<<5);
      float v=acc[r][c]+(c?bb1:bb0);
      if (ACT==1) v=gelu_f(v);
      if (ACT==2) v=silu_f(v);
      if (RES) v+=res[(size_t)row*N+col];
      C[(size_t)row*N+col]=v;
    }
  }
}

// gated FFN elementwise
__global__ void __launch_bounds__(256) k_gate(const float* __restrict__ ff, float* __restrict__ gv){
  int idx=blockIdx.x*256+threadIdx.x;
  if (idx<S*2048){
    int s2=idx>>11, m=idx&2047;
    float g=ff[s2*4096+m], v=ff[s2*4096+2048+m];
    gv[idx]=silu_f(g)*v;
  }
}

extern "C" void kernel_launch(void* const* d_in, const int* in_sizes, int n_in,
                              void* d_out, int out_size, void* d_ws, size_t ws_size,
                              hipStream_t stream){
  const float* x   =(const float*)d_in[0];
  const float* pat =(const float*)d_in[1];
  const float* sw1 =(const float*)d_in[2];
  const float* sb1 =(const float*)d_in[3];
  const float* sw2 =(const float*)d_in[4];
  const float* sb2 =(const float*)d_in[5];
  const float* ww1 =(const float*)d_in[6];
  const float* wb1 =(const float*)d_in[7];
  const float* ww2 =(const float*)d_in[8];
  const float* wb2 =(const float*)d_in[9];
  const float* iw1 =(const float*)d_in[10];
  const float* ib1 =(const float*)d_in[11];
  const float* iw2 =(const float*)d_in[12];
  const float* ib2 =(const float*)d_in[13];
  const float* mw1 =(const float*)d_in[14];
  const float* mb1 =(const float*)d_in[15];
  const float* mw2 =(const float*)d_in[16];
  const float* mb2 =(const float*)d_in[17];
  const float* bank=(const float*)d_in[18];
  const float* upw =(const float*)d_in[19];
  const float* upb =(const float*)d_in[20];
  const float* dww =(const float*)d_in[21];
  const float* dwb =(const float*)d_in[22];
  const float* n1g =(const float*)d_in[23];
  const float* n1b =(const float*)d_in[24];
  const float* n2g =(const float*)d_in[25];
  const float* n2b =(const float*)d_in[26];
  float* out=(float*)d_out;

  float* w = (float*)d_ws;
  float* xn     = w;                 // 131072
  float* xr     = xn+131072;         // 131072
  float* meanxr = xr+131072;         // 512
  float* memmean= meanxr+512;        // 512
  float* pwb    = memmean+512;       // 4096
  float* inten  = pwb+4096;          // 256
  float* ctxsel = inten+256;         // 32
  float* ctxint = ctxsel+32;         // 64
  float* mempart= ctxint+64;         // 512
  float* co     = mempart+512;       // 131072
  float* h1     = co+131072;         // 131072
  float* co2    = h1+131072;         // 131072
  float* ff     = co2+131072;        // 1048576
  float* gv     = ff+1048576;        // 524288
  int*   kkp    = (int*)(gv+524288);          // 4
  unsigned* meta= (unsigned*)(kkp+4);         // 1024
  // zeroed region: ghist (8192x256 u32) + gofl (256 u32)
  unsigned* ghist = (unsigned*)(meta+1024);   // 2097152 u32
  unsigned* gofl  = ghist+2097152;            // 256
  // plain-stored (no memset needed)
  float* goutr  = (float*)(gofl+256);         // 131072 f32
  float* goutrb = goutr+131072;               // 131072 f32
  unsigned* gcount=(unsigned*)(goutrb+131072);// 2048
  unsigned* gbits = gcount+2048;              // 2097152 u32
  float* gcon   = (float*)(gbits+2097152);    // 2097152 f32
  unsigned short* grow = (unsigned short*)(gcon+2097152); // 2097152 u16

  hipMemsetAsync(ghist, 0, (size_t)(2097152+256)*4, stream);

  k_ln_rope<<<S,256,0,stream>>>(x,n1g,n1b,xn,xr);
  k_colmean<<<4,256,0,stream>>>(xr,bank,meanxr,memmean);
  k_head<<<1,256,0,stream>>>(meanxr,memmean,ww1,wb1,ww2,wb2,sw1,sb1,iw1,ib1,mw1,mb1,
                             ctxsel,ctxint,mempart,kkp);
  k_selint<<<S,256,0,stream>>>(xr,ctxsel,ctxint,sw1,sw2,sb2,iw1,iw2,ib2,pwb,inten);
  k_fhist<<<dim3(64,4),1024,0,stream>>>(pat,pwb,ghist);
  k_fth<<<S,256,0,stream>>>(ghist,kkp,(unsigned*)meta);
  k_fmv<<<dim3(32,8),1024,0,stream>>>(pat,pwb,xn,(unsigned*)meta,goutr,goutrb,gbits,gcon,grow,gcount,gofl);
  k_fref<<<S,256,0,stream>>>(x,goutr,goutrb,(unsigned*)meta,gcount,gofl,gbits,gcon,grow,inten,n2g,n2b,co);
  k_gemm2<2,0,16><<<dim3(8,16),256,0,stream>>>(co, mw1, mempart, nullptr, h1, 512, 512);
  k_gemm2<0,1,16><<<dim3(8,16),256,0,stream>>>(h1, mw2, mb2, co, co2, 512, 512);
  k_gemm2<0,0,16><<<dim3(64,16),256,0,stream>>>(co2, upw, upb, nullptr, ff, 512, 4096);
  k_gate<<<2048,256,0,stream>>>(ff,gv);
  k_gemm2<0,1,16><<<dim3(8,16),256,0,stream>>>(gv, dww, dwb, co2, out, 2048, 512);
}

// Round 8
// 515.901 us; speedup vs baseline: 1.8165x; 1.8165x over previous
//
#include <hip/hip_runtime.h>
#include <math.h>

#define S 256
#define D 512
#define P 16
#define NIJ (D*D)
#define CCAP 1024   // per-(pos,chunk) candidate stash capacity

__device__ __forceinline__ float gelu_f(float x){ return 0.5f*x*(1.f+erff(x*0.70710678118654752f)); }
__device__ __forceinline__ float silu_f(float x){ return x/(1.f+expf(-x)); }
__device__ __forceinline__ float sigm_f(float x){ return 1.f/(1.f+expf(-x)); }

// K1: LayerNorm + RoPE per row
__global__ void __launch_bounds__(256) k_ln_rope(const float* __restrict__ x,
    const float* __restrict__ g, const float* __restrict__ b,
    float* __restrict__ xn, float* __restrict__ xr){
  int s2 = blockIdx.x, tid = threadIdx.x;
  __shared__ float red[256];
  __shared__ float xnl[512];
  const float* xrow = x + s2*D;
  float v0 = xrow[tid], v1 = xrow[tid+256];
  red[tid] = v0+v1; __syncthreads();
  for (int st=128; st>0; st>>=1){ if (tid<st) red[tid]+=red[tid+st]; __syncthreads(); }
  float mean = red[0]*(1.f/512.f); __syncthreads();
  float d0=v0-mean, d1=v1-mean;
  red[tid]=d0*d0+d1*d1; __syncthreads();
  for (int st=128; st>0; st>>=1){ if (tid<st) red[tid]+=red[tid+st]; __syncthreads(); }
  float var = red[0]*(1.f/512.f);
  float rstd = rsqrtf(var+1e-5f);
  float a0 = d0*rstd*g[tid]+b[tid];
  float a1 = d1*rstd*g[tid+256]+b[tid+256];
  xn[s2*D+tid]=a0; xn[s2*D+tid+256]=a1;
  xnl[tid]=a0; xnl[tid+256]=a1;
  __syncthreads();
  int j = tid;
  float e = (float)(2*j)*(1.f/512.f);
  float inv = 1.f/powf(10000.f, e);
  float ang = (float)s2 * inv;
  float c = cosf(ang), sn = sinf(ang);
  float p0 = xnl[2*j], p1 = xnl[2*j+1];
  xr[s2*D+2*j]   = p0*c - p1*sn;
  xr[s2*D+2*j+1] = p1*c + p0*sn;
}

// K2: column means
__global__ void __launch_bounds__(256) k_colmean(const float* __restrict__ xr,
    const float* __restrict__ bank, float* __restrict__ meanxr, float* __restrict__ memmean){
  int tid=threadIdx.x;
  if (blockIdx.x<2){
    int d2 = blockIdx.x*256+tid; float acc=0.f;
    for (int s2=0;s2<S;++s2) acc += xr[s2*D+d2];
    meanxr[d2]=acc*(1.f/256.f);
  } else {
    int d2=(blockIdx.x-2)*256+tid; float acc=0.f;
    for (int r=0;r<512;++r) acc += bank[r*D+d2];
    memmean[d2]=acc*(1.f/512.f);
  }
}

// K3: window MLP -> kk; fold ctx/mem halves into effective biases
__global__ void __launch_bounds__(256) k_head(const float* __restrict__ meanxr, const float* __restrict__ memmean,
    const float* __restrict__ ww1, const float* __restrict__ wb1,
    const float* __restrict__ ww2, const float* __restrict__ wb2,
    const float* __restrict__ sw1, const float* __restrict__ sb1,
    const float* __restrict__ iw1, const float* __restrict__ ib1,
    const float* __restrict__ mw1, const float* __restrict__ mb1,
    float* __restrict__ ctxsel, float* __restrict__ ctxint,
    float* __restrict__ mempart, int* __restrict__ kkout){
  int tid=threadIdx.x;
  __shared__ float mx[512], mm[512], gw[64];
  mx[tid]=meanxr[tid]; mx[tid+256]=meanxr[tid+256];
  mm[tid]=memmean[tid]; mm[tid+256]=memmean[tid+256];
  __syncthreads();
  if (tid<64){ float a=wb1[tid]; for (int d2=0;d2<512;++d2) a=fmaf(mx[d2], ww1[d2*64+tid], a); gw[tid]=gelu_f(a); }
  __syncthreads();
  if (tid==0){
    float a=wb2[0]; for (int h=0;h<64;++h) a=fmaf(gw[h], ww2[h], a);
    float win = sigm_f(a)*3840.f+256.f;
    float asp = 0.1f*(win*(1.f/4096.f));
    float t = 262144.f*asp;
    int kk=(int)t; if (kk<1) kk=1;
    *kkout=kk;
  }
  if (tid<32){ float a=sb1[tid]; for (int d2=0;d2<512;++d2) a=fmaf(mx[d2], sw1[(512+d2)*32+tid], a); ctxsel[tid]=a; }
  if (tid>=64 && tid<128){ int o=tid-64; float a=ib1[o]; for (int d2=0;d2<512;++d2) a=fmaf(mx[d2], iw1[(512+d2)*64+o], a); ctxint[o]=a; }
  for (int o=tid;o<512;o+=256){ float a=mb1[o]; for (int d2=0;d2<512;++d2) a=fmaf(mm[d2], mw1[(512+d2)*512+o], a); mempart[o]=a; }
}

// K4: per-position selection MLP (softmax pw) + intensity
__global__ void __launch_bounds__(256) k_selint(const float* __restrict__ xr,
    const float* __restrict__ ctxsel, const float* __restrict__ ctxint,
    const float* __restrict__ sw1, const float* __restrict__ sw2, const float* __restrict__ sb2,
    const float* __restrict__ iw1, const float* __restrict__ iw2, const float* __restrict__ ib2,
    float* __restrict__ pw, float* __restrict__ inten){
  int s2=blockIdx.x, tid=threadIdx.x;
  __shared__ float xl[512]; __shared__ float h1[32], h2[64], lg[16];
  xl[tid]=xr[s2*D+tid]; xl[tid+256]=xr[s2*D+tid+256];
  __syncthreads();
  if (tid<32){ float a=ctxsel[tid]; for (int d2=0;d2<512;++d2) a=fmaf(xl[d2], sw1[d2*32+tid], a); h1[tid]=gelu_f(a); }
  else if (tid<96){ int o=tid-32; float a=ctxint[o]; for (int d2=0;d2<512;++d2) a=fmaf(xl[d2], iw1[d2*64+o], a); h2[o]=gelu_f(a); }
  __syncthreads();
  if (tid<16){ float a=sb2[tid]; for (int h=0;h<32;++h) a=fmaf(h1[h], sw2[h*16+tid], a); lg[tid]=a; }
  __syncthreads();
  if (tid==0){
    float m=lg[0]; for (int p2=1;p2<16;++p2) m=fmaxf(m,lg[p2]);
    float sm=0.f; float e[16];
    for (int p2=0;p2<16;++p2){ e[p2]=expf(lg[p2]-m); sm+=e[p2]; }
    float r=1.f/sm;
    for (int p2=0;p2<16;++p2) pw[s2*16+p2]=e[p2]*r;
  }
  if (tid==64){ float a=ib2[0]; for (int h=0;h<64;++h) a=fmaf(h2[h], iw2[h], a); inten[s2]=sigm_f(a); }
}

// K5a: shared-sweep histogram. grid (32 pos-groups, 8 chunks); 8 pos/block.
// 13-bit bins (abs bits >> 18). Paired u16 counts: hist word = pos(2k) lo16 | pos(2k+1) hi16.
// Per-chunk per-pos values = 32768 < 65536 so no overflow.
__global__ __launch_bounds__(1024) __attribute__((amdgpu_waves_per_eu(4,4)))
void k_fhist(const float* __restrict__ pat,
    const float* __restrict__ pw, unsigned* __restrict__ ghist){
  __shared__ unsigned hist[4*8192];   // 128KB
  __shared__ float pws8[128];
  int g=blockIdx.x, c=blockIdx.y, tid=threadIdx.x;
  if (tid<128) pws8[tid]=pw[g*128+tid];
  for (int i=tid;i<32768;i+=1024) hist[i]=0u;
  __syncthreads();
  const float4* patv=(const float4*)pat;
  for (int it=0;it<8;++it){
    int f4=(c<<13)+(it<<10)+tid;
    float4 acc[8];
    #pragma unroll
    for (int pp=0;pp<8;++pp) acc[pp]=make_float4(0.f,0.f,0.f,0.f);
    #pragma unroll 4
    for (int p=0;p<16;++p){
      float4 pv=patv[(p<<16)+f4];
      #pragma unroll
      for (int pp=0;pp<8;++pp){
        float w=pws8[(pp<<4)+p];
        acc[pp].x=fmaf(w,pv.x,acc[pp].x); acc[pp].y=fmaf(w,pv.y,acc[pp].y);
        acc[pp].z=fmaf(w,pv.z,acc[pp].z); acc[pp].w=fmaf(w,pv.w,acc[pp].w);
      }
    }
    #pragma unroll
    for (int pp=0;pp<8;++pp){
      unsigned add=(pp&1)?0x10000u:1u;
      unsigned* h=&hist[(pp>>1)<<13];
      atomicAdd(&h[(__float_as_uint(acc[pp].x)&0x7fffffffu)>>18],add);
      atomicAdd(&h[(__float_as_uint(acc[pp].y)&0x7fffffffu)>>18],add);
      atomicAdd(&h[(__float_as_uint(acc[pp].z)&0x7fffffffu)>>18],add);
      atomicAdd(&h[(__float_as_uint(acc[pp].w)&0x7fffffffu)>>18],add);
    }
  }
  __syncthreads();
  for (int i=tid;i<32768;i+=1024){
    unsigned v=hist[i];
    if (v){
      int pair=i>>13, bin=i&8191;
      int pos0=(g<<3)+(pair<<1);
      unsigned lo=v&0xffffu, hi=v>>16;
      if (lo) atomicAdd(&ghist[(pos0<<13)+bin], lo);
      if (hi) atomicAdd(&ghist[((pos0+1)<<13)+bin], hi);
    }
  }
}

// K5b: per-position threshold bin from 8192-bin global histogram.
__global__ void __launch_bounds__(256) k_fth(const unsigned* __restrict__ ghist,
    const int* __restrict__ kkin, unsigned* __restrict__ meta){
  int pos=blockIdx.x, tid=threadIdx.x;
  __shared__ unsigned part[256]; __shared__ unsigned sup[16];
  const unsigned* h=ghist+(pos<<13);
  unsigned s=0;
  for (int k=0;k<32;++k) s+=h[tid*32+k];
  part[tid]=s; __syncthreads();
  if (tid<16){ unsigned t=0; for (int k=0;k<16;++k) t+=part[tid*16+k]; sup[tid]=t; }
  __syncthreads();
  if (tid==0){
    unsigned kk=(unsigned)(*kkin);
    unsigned cum=0; int u=0;
    for (int j=15;j>=0;--j){ if (cum+sup[j]>=kk){ u=j; break; } cum+=sup[j]; }
    int t=u*16;
    for (int j=u*16+15;j>=u*16;--j){ if (cum+part[j]>=kk){ t=j; break; } cum+=part[j]; }
    int b=t*32;
    for (int j=t*32+31;j>=t*32;--j){ if (cum+h[j]>=kk){ b=j; break; } cum+=h[j]; }
    meta[pos*4+0]=(unsigned)b; meta[pos*4+1]=kk-cum; meta[pos*4+2]=h[b];
  }
}

// K5c: shared-sweep masked matvec. grid (32 pos-groups, 8 chunks); 8 pos/block.
// p-outer/pp-inner keeps live VGPR ~70. Wave shuffle-reduce for the main sum;
// rare threshold-bin contributions go via per-lane LDS atomics.
__global__ __launch_bounds__(1024) __attribute__((amdgpu_waves_per_eu(4,4)))
void k_fmv(const float* __restrict__ pat,
    const float* __restrict__ pw, const float* __restrict__ xn,
    const unsigned* __restrict__ meta, float* __restrict__ goutr, float* __restrict__ goutrb,
    unsigned* __restrict__ gbits, float* __restrict__ gcon,
    unsigned short* __restrict__ grow, unsigned* __restrict__ gcount, unsigned* __restrict__ gofl){
  __shared__ float pws8[128];
  __shared__ float xnl[4096];
  __shared__ float outr[512];   // 8 pos x 64 rows (this chunk's rows)
  __shared__ float outrb[512];  // threshold-bin sums per row (fallback path)
  __shared__ unsigned lcnt[8];
  int g=blockIdx.x, c=blockIdx.y, tid=threadIdx.x;
  if (tid<128) pws8[tid]=pw[g*128+tid];
  for (int i=tid;i<4096;i+=1024) xnl[i]=xn[(g<<12)+i];
  if (tid<512){ outr[tid]=0.f; outrb[tid]=0.f; }
  if (tid<8) lcnt[tid]=0u;
  __syncthreads();
  unsigned bst[8];
  #pragma unroll
  for (int pp=0;pp<8;++pp) bst[pp]=meta[((g<<3)+pp)*4];
  const float4* patv=(const float4*)pat;
  int lane=tid&63;
  for (int it=0;it<8;++it){
    int f4=(c<<13)+(it<<10)+tid;
    int rowg=f4>>7;             // global row 0..511
    int row=rowg&63;            // local row in this chunk
    int col0=(f4&127)<<2;
    float4 acc[8];
    #pragma unroll
    for (int pp=0;pp<8;++pp) acc[pp]=make_float4(0.f,0.f,0.f,0.f);
    #pragma unroll 4
    for (int p=0;p<16;++p){
      float4 pv=patv[(p<<16)+f4];
      #pragma unroll
      for (int pp=0;pp<8;++pp){
        float w=pws8[(pp<<4)+p];
        acc[pp].x=fmaf(w,pv.x,acc[pp].x); acc[pp].y=fmaf(w,pv.y,acc[pp].y);
        acc[pp].z=fmaf(w,pv.z,acc[pp].z); acc[pp].w=fmaf(w,pv.w,acc[pp].w);
      }
    }
    #pragma unroll
    for (int pp=0;pp<8;++pp){
      float4 xq=*(const float4*)&xnl[(pp<<9)+col0];
      float vv[4]={acc[pp].x,acc[pp].y,acc[pp].z,acc[pp].w};
      float xv[4]={xq.x,xq.y,xq.z,xq.w};
      float lacc=0.f;
      #pragma unroll
      for (int q=0;q<4;++q){
        unsigned bits=__float_as_uint(vv[q])&0x7fffffffu;
        unsigned pfx=bits>>18;
        if (pfx>bst[pp]) lacc=fmaf(vv[q],xv[q],lacc);
        else if (pfx==bst[pp]){
          float con=vv[q]*xv[q];
          atomicAdd(&outrb[(pp<<6)+row], con);
          unsigned idx=atomicAdd(&lcnt[pp],1u);
          if (idx<CCAP){
            int o=((((g<<3)+pp)<<3)+c)*CCAP+idx;
            gbits[o]=bits; gcon[o]=con; grow[o]=(unsigned short)rowg;
          }
        }
      }
      #pragma unroll
      for (int m=32;m>0;m>>=1) lacc+=__shfl_xor(lacc,m,64);
      if (lane==0 && lacc!=0.f) atomicAdd(&outr[(pp<<6)+row], lacc);
    }
  }
  __syncthreads();
  if (tid<512){
    int pp=tid>>6, r=tid&63;
    goutr [((g<<3)+pp)*512+(c<<6)+r]=outr[tid];
    goutrb[((g<<3)+pp)*512+(c<<6)+r]=outrb[tid];
  }
  if (tid<8){
    unsigned n=lcnt[tid];
    gcount[((g<<3)+tid)*8+c]=n;
    if (n>CCAP) gofl[(g<<3)+tid]=1u;
  }
}

// K5d: per-position exact refinement over stashed candidates + apply + residual + LN2.
__global__ void __launch_bounds__(256) k_fref(const float* __restrict__ x,
    const float* __restrict__ goutr, const float* __restrict__ goutrb,
    const unsigned* __restrict__ meta, const unsigned* __restrict__ gcount,
    const unsigned* __restrict__ gofl, const unsigned* __restrict__ gbits,
    const float* __restrict__ gcon, const unsigned short* __restrict__ grow,
    const float* __restrict__ inten, const float* __restrict__ n2g, const float* __restrict__ n2b,
    float* __restrict__ co){
  int pos=blockIdx.x, tid=threadIdx.x;
  __shared__ float outr[512]; __shared__ unsigned rhist[2048]; __shared__ unsigned rpart[128];
  __shared__ unsigned thsh[4]; __shared__ float red[256];
  outr[tid]=goutr[pos*512+tid]; outr[tid+256]=goutr[pos*512+tid+256];
  unsigned bstar=meta[pos*4], rnk=meta[pos*4+1];
  bool ofl = gofl[pos]!=0u;
  if (ofl){
    outr[tid]+=goutrb[pos*512+tid]; outr[tid+256]+=goutrb[pos*512+tid+256];
    __syncthreads();
  } else {
    for (int i=tid;i<2048;i+=256) rhist[i]=0u;
    __syncthreads();
    for (int c=0;c<8;++c){
      unsigned n=gcount[pos*8+c]; if (n>CCAP) n=CCAP;
      const unsigned* cb=gbits+(((pos<<3)+c)*CCAP);
      for (unsigned i=tid;i<n;i+=256) atomicAdd(&rhist[(cb[i]>>7)&0x7ffu],1u);
    }
    __syncthreads();
    if (tid<128){ unsigned t=0;
      #pragma unroll
      for (int k=0;k<16;++k) t+=rhist[tid*16+k];
      rpart[tid]=t; }
    __syncthreads();
    if (tid==0){
      unsigned cum=0; int rp=0;
      for (int j=127;j>=0;--j){ if (cum+rpart[j]>=rnk){ rp=j; break; } cum+=rpart[j]; }
      int sub=rp*16;
      for (int j=rp*16+15;j>=rp*16;--j){ if (cum+rhist[j]>=rnk){ sub=j; break; } cum+=rhist[j]; }
      thsh[0]=(unsigned)sub; thsh[1]=rnk-cum;
    }
    __syncthreads();
    unsigned sub=thsh[0], r2=thsh[1];
    if (tid<128) rhist[tid]=0u;
    __syncthreads();
    for (int c=0;c<8;++c){
      unsigned n=gcount[pos*8+c]; if (n>CCAP) n=CCAP;
      const unsigned* cb=gbits+(((pos<<3)+c)*CCAP);
      for (unsigned i=tid;i<n;i+=256) if (((cb[i]>>7)&0x7ffu)==sub) atomicAdd(&rhist[cb[i]&127u],1u);
    }
    __syncthreads();
    if (tid==0){
      unsigned cum=0; unsigned lo=0;
      for (int j=127;j>=0;--j){ if (cum+rhist[j]>=r2){ lo=(unsigned)j; break; } cum+=rhist[j]; }
      thsh[2]=(bstar<<18)|(sub<<7)|lo;
    }
    __syncthreads();
    unsigned thb=thsh[2];
    for (int c=0;c<8;++c){
      unsigned n=gcount[pos*8+c]; if (n>CCAP) n=CCAP;
      int base=((pos<<3)+c)*CCAP;
      for (unsigned i=tid;i<n;i+=256)
        if (gbits[base+i]>=thb) atomicAdd(&outr[grow[base+i]], gcon[base+i]);
    }
  }
  __syncthreads();
  float it=inten[pos];
  float t0=x[pos*D+tid]+outr[tid]*it;
  float t1=x[pos*D+tid+256]+outr[tid+256]*it;
  red[tid]=t0+t1; __syncthreads();
  for (int st=128;st>0;st>>=1){ if (tid<st) red[tid]+=red[tid+st]; __syncthreads(); }
  float mean=red[0]*(1.f/512.f); __syncthreads();
  float d0=t0-mean, d1=t1-mean;
  red[tid]=d0*d0+d1*d1; __syncthreads();
  for (int st=128;st>0;st>>=1){ if (tid<st) red[tid]+=red[tid+st]; __syncthreads(); }
  float var=red[0]*(1.f/512.f);
  float rstd=rsqrtf(var+1e-5f);
  co[pos*D+tid]=d0*rstd*n2g[tid]+n2b[tid];
  co[pos*D+tid+256]=d1*rstd*n2g[tid+256]+n2b[tid+256];
}

// ---------------- GEMM: RTx64 tile, LDS-staged, prefetch ----------------
template<int ACT, int RES, int RT>
__global__ void __launch_bounds__(256) k_gemm2(const float* __restrict__ A, const float* __restrict__ W,
    const float* __restrict__ bias, const float* __restrict__ res,
    float* __restrict__ C, int K, int N){
  __shared__ float Ast[32][RT+4];
  __shared__ float Ws[32][68];
  const int RPT=RT/8;
  int tid=threadIdx.x;
  int cb=blockIdx.x<<6;
  int s0=blockIdx.y*RT;
  int rid=tid>>5;
  int cid=tid&31;
  int arow=tid>>3, akq=tid&7;
  int wrow=tid>>4, wc4=tid&15;
  bool aload = tid < RT*8;
  float acc[RPT][2];
  #pragma unroll
  for (int r=0;r<RPT;++r){ acc[r][0]=0.f; acc[r][1]=0.f; }
  const float* Aptr = A + (size_t)(s0+arow)*K + (akq<<2);
  const float* Wptr0 = W + (size_t)wrow*N + cb + (wc4<<2);
  const float* Wptr1 = W + (size_t)(wrow+16)*N + cb + (wc4<<2);
  float4 av=make_float4(0.f,0.f,0.f,0.f);
  if (aload) av=*(const float4*)Aptr;
  float4 w0=*(const float4*)Wptr0;
  float4 w1=*(const float4*)Wptr1;
  for (int k0=0;k0<K;k0+=32){
    if (aload){
      Ast[(akq<<2)+0][arow]=av.x; Ast[(akq<<2)+1][arow]=av.y;
      Ast[(akq<<2)+2][arow]=av.z; Ast[(akq<<2)+3][arow]=av.w;
    }
    *(float4*)&Ws[wrow][wc4<<2]=w0;
    *(float4*)&Ws[wrow+16][wc4<<2]=w1;
    __syncthreads();
    if (k0+32<K){
      if (aload) av=*(const float4*)(Aptr + k0+32);
      w0=*(const float4*)(Wptr0 + (size_t)(k0+32)*N);
      w1=*(const float4*)(Wptr1 + (size_t)(k0+32)*N);
    }
    #pragma unroll
    for (int kk=0;kk<32;++kk){
      float b0=Ws[kk][cid], b1=Ws[kk][cid+32];
      if constexpr (RPT==4){
        float4 a4=*(const float4*)&Ast[kk][rid<<2];
        acc[0][0]=fmaf(a4.x,b0,acc[0][0]); acc[0][1]=fmaf(a4.x,b1,acc[0][1]);
        acc[1][0]=fmaf(a4.y,b0,acc[1][0]); acc[1][1]=fmaf(a4.y,b1,acc[1][1]);
        acc[2][0]=fmaf(a4.z,b0,acc[2][0]); acc[2][1]=fmaf(a4.z,b1,acc[2][1]);
        acc[3][0]=fmaf(a4.w,b0,acc[3][0]); acc[3][1]=fmaf(a4.w,b1,acc[3][1]);
      } else {
        float2 a2=*(const float2*)&Ast[kk][rid<<1];
        acc[0][0]=fmaf(a2.x,b0,acc[0][0]); acc[0][1]=fmaf(a2.x,b1,acc[0][1]);
        acc[1][0]=fmaf(a2.y,b0,acc[1][0]); acc[1][1]=fmaf(a2.y,b1,acc[1][1]);
      }
    }
    __syncthreads();
  }
  float bb0=bias[cb+cid], bb1=bias[cb+cid+32];
  #pragma unroll
  for (int r=0;r<RPT;++r){
    int row=s0+rid*RPT+r;
    #pragma unroll
    for (int c=0;c<2;++c){
      int col=cb+cid+(c<<5);
      float v=acc[r][c]+(c?bb1:bb0);
      if (ACT==1) v=gelu_f(v);
      if (ACT==2) v=silu_f(v);
      if (RES) v+=res[(size_t)row*N+col];
      C[(size_t)row*N+col]=v;
    }
  }
}

// gated FFN elementwise
__global__ void __launch_bounds__(256) k_gate(const float* __restrict__ ff, float* __restrict__ gv){
  int idx=blockIdx.x*256+threadIdx.x;
  if (idx<S*2048){
    int s2=idx>>11, m=idx&2047;
    float g=ff[s2*4096+m], v=ff[s2*4096+2048+m];
    gv[idx]=silu_f(g)*v;
  }
}

extern "C" void kernel_launch(void* const* d_in, const int* in_sizes, int n_in,
                              void* d_out, int out_size, void* d_ws, size_t ws_size,
                              hipStream_t stream){
  const float* x   =(const float*)d_in[0];
  const float* pat =(const float*)d_in[1];
  const float* sw1 =(const float*)d_in[2];
  const float* sb1 =(const float*)d_in[3];
  const float* sw2 =(const float*)d_in[4];
  const float* sb2 =(const float*)d_in[5];
  const float* ww1 =(const float*)d_in[6];
  const float* wb1 =(const float*)d_in[7];
  const float* ww2 =(const float*)d_in[8];
  const float* wb2 =(const float*)d_in[9];
  const float* iw1 =(const float*)d_in[10];
  const float* ib1 =(const float*)d_in[11];
  const float* iw2 =(const float*)d_in[12];
  const float* ib2 =(const float*)d_in[13];
  const float* mw1 =(const float*)d_in[14];
  const float* mb1 =(const float*)d_in[15];
  const float* mw2 =(const float*)d_in[16];
  const float* mb2 =(const float*)d_in[17];
  const float* bank=(const float*)d_in[18];
  const float* upw =(const float*)d_in[19];
  const float* upb =(const float*)d_in[20];
  const float* dww =(const float*)d_in[21];
  const float* dwb =(const float*)d_in[22];
  const float* n1g =(const float*)d_in[23];
  const float* n1b =(const float*)d_in[24];
  const float* n2g =(const float*)d_in[25];
  const float* n2b =(const float*)d_in[26];
  float* out=(float*)d_out;

  float* w = (float*)d_ws;
  float* xn     = w;                 // 131072
  float* xr     = xn+131072;         // 131072
  float* meanxr = xr+131072;         // 512
  float* memmean= meanxr+512;        // 512
  float* pwb    = memmean+512;       // 4096
  float* inten  = pwb+4096;          // 256
  float* ctxsel = inten+256;         // 32
  float* ctxint = ctxsel+32;         // 64
  float* mempart= ctxint+64;         // 512
  float* co     = mempart+512;       // 131072
  float* h1     = co+131072;         // 131072
  float* co2    = h1+131072;         // 131072
  float* ff     = co2+131072;        // 1048576
  float* gv     = ff+1048576;        // 524288
  int*   kkp    = (int*)(gv+524288);          // 4
  unsigned* meta= (unsigned*)(kkp+4);         // 1024
  // zeroed region: ghist (8192x256 u32) + gofl (256 u32)
  unsigned* ghist = (unsigned*)(meta+1024);   // 2097152 u32
  unsigned* gofl  = ghist+2097152;            // 256
  // plain-stored (no memset needed)
  float* goutr  = (float*)(gofl+256);         // 131072 f32
  float* goutrb = goutr+131072;               // 131072 f32
  unsigned* gcount=(unsigned*)(goutrb+131072);// 2048
  unsigned* gbits = gcount+2048;              // 2097152 u32
  float* gcon   = (float*)(gbits+2097152);    // 2097152 f32
  unsigned short* grow = (unsigned short*)(gcon+2097152); // 2097152 u16

  hipMemsetAsync(ghist, 0, (size_t)(2097152+256)*4, stream);

  k_ln_rope<<<S,256,0,stream>>>(x,n1g,n1b,xn,xr);
  k_colmean<<<4,256,0,stream>>>(xr,bank,meanxr,memmean);
  k_head<<<1,256,0,stream>>>(meanxr,memmean,ww1,wb1,ww2,wb2,sw1,sb1,iw1,ib1,mw1,mb1,
                             ctxsel,ctxint,mempart,kkp);
  k_selint<<<S,256,0,stream>>>(xr,ctxsel,ctxint,sw1,sw2,sb2,iw1,iw2,ib2,pwb,inten);
  k_fhist<<<dim3(32,8),1024,0,stream>>>(pat,pwb,ghist);
  k_fth<<<S,256,0,stream>>>(ghist,kkp,(unsigned*)meta);
  k_fmv<<<dim3(32,8),1024,0,stream>>>(pat,pwb,xn,(unsigned*)meta,goutr,goutrb,gbits,gcon,grow,gcount,gofl);
  k_fref<<<S,256,0,stream>>>(x,goutr,goutrb,(unsigned*)meta,gcount,gofl,gbits,gcon,grow,inten,n2g,n2b,co);
  k_gemm2<2,0,16><<<dim3(8,16),256,0,stream>>>(co, mw1, mempart, nullptr, h1, 512, 512);
  k_gemm2<0,1,16><<<dim3(8,16),256,0,stream>>>(h1, mw2, mb2, co, co2, 512, 512);
  k_gemm2<0,0,16><<<dim3(64,16),256,0,stream>>>(co2, upw, upb, nullptr, ff, 512, 4096);
  k_gate<<<2048,256,0,stream>>>(ff,gv);
  k_gemm2<0,1,16><<<dim3(8,16),256,0,stream>>>(gv, dww, dwb, co2, out, 2048, 512);
}

// Round 9
// 466.979 us; speedup vs baseline: 2.0068x; 1.1048x over previous
//
#include <hip/hip_runtime.h>
#include <math.h>

#define S 256
#define D 512
#define P 16
#define NIJ (D*D)
#define CCAP 1024   // per-(pos,chunk) candidate stash capacity

__device__ __forceinline__ float gelu_f(float x){ return 0.5f*x*(1.f+erff(x*0.70710678118654752f)); }
__device__ __forceinline__ float silu_f(float x){ return x/(1.f+expf(-x)); }
__device__ __forceinline__ float sigm_f(float x){ return 1.f/(1.f+expf(-x)); }

// K1: LayerNorm + RoPE per row
__global__ void __launch_bounds__(256) k_ln_rope(const float* __restrict__ x,
    const float* __restrict__ g, const float* __restrict__ b,
    float* __restrict__ xn, float* __restrict__ xr){
  int s2 = blockIdx.x, tid = threadIdx.x;
  __shared__ float red[256];
  __shared__ float xnl[512];
  const float* xrow = x + s2*D;
  float v0 = xrow[tid], v1 = xrow[tid+256];
  red[tid] = v0+v1; __syncthreads();
  for (int st=128; st>0; st>>=1){ if (tid<st) red[tid]+=red[tid+st]; __syncthreads(); }
  float mean = red[0]*(1.f/512.f); __syncthreads();
  float d0=v0-mean, d1=v1-mean;
  red[tid]=d0*d0+d1*d1; __syncthreads();
  for (int st=128; st>0; st>>=1){ if (tid<st) red[tid]+=red[tid+st]; __syncthreads(); }
  float var = red[0]*(1.f/512.f);
  float rstd = rsqrtf(var+1e-5f);
  float a0 = d0*rstd*g[tid]+b[tid];
  float a1 = d1*rstd*g[tid+256]+b[tid+256];
  xn[s2*D+tid]=a0; xn[s2*D+tid+256]=a1;
  xnl[tid]=a0; xnl[tid+256]=a1;
  __syncthreads();
  int j = tid;
  float e = (float)(2*j)*(1.f/512.f);
  float inv = 1.f/powf(10000.f, e);
  float ang = (float)s2 * inv;
  float c = cosf(ang), sn = sinf(ang);
  float p0 = xnl[2*j], p1 = xnl[2*j+1];
  xr[s2*D+2*j]   = p0*c - p1*sn;
  xr[s2*D+2*j+1] = p1*c + p0*sn;
}

// K2: column means
__global__ void __launch_bounds__(256) k_colmean(const float* __restrict__ xr,
    const float* __restrict__ bank, float* __restrict__ meanxr, float* __restrict__ memmean){
  int tid=threadIdx.x;
  if (blockIdx.x<2){
    int d2 = blockIdx.x*256+tid; float acc=0.f;
    for (int s2=0;s2<S;++s2) acc += xr[s2*D+d2];
    meanxr[d2]=acc*(1.f/256.f);
  } else {
    int d2=(blockIdx.x-2)*256+tid; float acc=0.f;
    for (int r=0;r<512;++r) acc += bank[r*D+d2];
    memmean[d2]=acc*(1.f/512.f);
  }
}

// K3a: parallel fold GEMVs. 21 blocks x 32 outputs.
// b 0..15: mempart[512] (memmean . mw1[512+d][o]), b 16..17: ctxint[64],
// b 18: ctxsel[32], b 19..20: gw[64] = gelu(meanxr . ww1[d][o] + wb1)
__global__ void __launch_bounds__(256) k_fold(const float* __restrict__ meanxr,
    const float* __restrict__ memmean,
    const float* __restrict__ mw1, const float* __restrict__ mb1,
    const float* __restrict__ iw1, const float* __restrict__ ib1,
    const float* __restrict__ sw1, const float* __restrict__ sb1,
    const float* __restrict__ ww1, const float* __restrict__ wb1,
    float* __restrict__ mempart, float* __restrict__ ctxint,
    float* __restrict__ ctxsel, float* __restrict__ gw){
  __shared__ float vec[512];
  __shared__ float red[256];
  int b=blockIdx.x, tid=threadIdx.x;
  int seg, obase; const float* W; const float* bias; float* outp; int N; int rowoff;
  if (b<16){ seg=0; obase=b*32; W=mw1; bias=mb1; outp=mempart; N=512; rowoff=512; }
  else if (b<18){ seg=1; obase=(b-16)*32; W=iw1; bias=ib1; outp=ctxint; N=64; rowoff=512; }
  else if (b<19){ seg=2; obase=0; W=sw1; bias=sb1; outp=ctxsel; N=32; rowoff=512; }
  else { seg=3; obase=(b-19)*32; W=ww1; bias=wb1; outp=gw; N=64; rowoff=0; }
  const float* v=(seg==0)?memmean:meanxr;
  vec[tid]=v[tid]; vec[tid+256]=v[tid+256];
  __syncthreads();
  int ol=tid&31, ch=tid>>5;
  float a=0.f;
  int d0=ch*64;
  for (int d=d0; d<d0+64; ++d) a=fmaf(vec[d], W[(size_t)(rowoff+d)*N+obase+ol], a);
  red[tid]=a; __syncthreads();
  if (tid<32){
    float s=bias[obase+tid];
    #pragma unroll
    for (int k=0;k<8;++k) s+=red[k*32+tid];
    if (seg==3) s=gelu_f(s);
    outp[obase+tid]=s;
  }
}

// K3b: window head -> kk
__global__ void k_kk(const float* __restrict__ gw, const float* __restrict__ ww2,
    const float* __restrict__ wb2, int* __restrict__ kkout){
  int tid=threadIdx.x;  // 64
  float a=gw[tid]*ww2[tid];
  #pragma unroll
  for (int m=32;m>0;m>>=1) a+=__shfl_xor(a,m,64);
  if (tid==0){
    float win=sigm_f(a+wb2[0])*3840.f+256.f;
    float asp=0.1f*(win*(1.f/4096.f));
    float t=262144.f*asp;
    int kk=(int)t; if (kk<1) kk=1;
    *kkout=kk;
  }
}

// K4: per-position selection MLP (softmax pw) + intensity
__global__ void __launch_bounds__(256) k_selint(const float* __restrict__ xr,
    const float* __restrict__ ctxsel, const float* __restrict__ ctxint,
    const float* __restrict__ sw1, const float* __restrict__ sw2, const float* __restrict__ sb2,
    const float* __restrict__ iw1, const float* __restrict__ iw2, const float* __restrict__ ib2,
    float* __restrict__ pw, float* __restrict__ inten){
  int s2=blockIdx.x, tid=threadIdx.x;
  __shared__ float xl[512]; __shared__ float h1[32], h2[64], lg[16];
  xl[tid]=xr[s2*D+tid]; xl[tid+256]=xr[s2*D+tid+256];
  __syncthreads();
  if (tid<32){ float a=ctxsel[tid]; for (int d2=0;d2<512;++d2) a=fmaf(xl[d2], sw1[d2*32+tid], a); h1[tid]=gelu_f(a); }
  else if (tid<96){ int o=tid-32; float a=ctxint[o]; for (int d2=0;d2<512;++d2) a=fmaf(xl[d2], iw1[d2*64+o], a); h2[o]=gelu_f(a); }
  __syncthreads();
  if (tid<16){ float a=sb2[tid]; for (int h=0;h<32;++h) a=fmaf(h1[h], sw2[h*16+tid], a); lg[tid]=a; }
  __syncthreads();
  if (tid==0){
    float m=lg[0]; for (int p2=1;p2<16;++p2) m=fmaxf(m,lg[p2]);
    float sm=0.f; float e[16];
    for (int p2=0;p2<16;++p2){ e[p2]=expf(lg[p2]-m); sm+=e[p2]; }
    float r=1.f/sm;
    for (int p2=0;p2<16;++p2) pw[s2*16+p2]=e[p2]*r;
  }
  if (tid==64){ float a=ib2[0]; for (int h=0;h<64;++h) a=fmaf(h2[h], iw2[h], a); inten[s2]=sigm_f(a); }
}

// K5a: shared-sweep histogram. grid (32 pos-groups, 8 chunks); 8 pos/block.
__global__ __launch_bounds__(1024) __attribute__((amdgpu_waves_per_eu(4,4)))
void k_fhist(const float* __restrict__ pat,
    const float* __restrict__ pw, unsigned* __restrict__ ghist){
  __shared__ unsigned hist[4*8192];   // 128KB
  __shared__ float pws8[128];
  int g=blockIdx.x, c=blockIdx.y, tid=threadIdx.x;
  if (tid<128) pws8[tid]=pw[g*128+tid];
  for (int i=tid;i<32768;i+=1024) hist[i]=0u;
  __syncthreads();
  const float4* patv=(const float4*)pat;
  for (int it=0;it<8;++it){
    int f4=(c<<13)+(it<<10)+tid;
    float4 acc[8];
    #pragma unroll
    for (int pp=0;pp<8;++pp) acc[pp]=make_float4(0.f,0.f,0.f,0.f);
    #pragma unroll 4
    for (int p=0;p<16;++p){
      float4 pv=patv[(p<<16)+f4];
      #pragma unroll
      for (int pp=0;pp<8;++pp){
        float w=pws8[(pp<<4)+p];
        acc[pp].x=fmaf(w,pv.x,acc[pp].x); acc[pp].y=fmaf(w,pv.y,acc[pp].y);
        acc[pp].z=fmaf(w,pv.z,acc[pp].z); acc[pp].w=fmaf(w,pv.w,acc[pp].w);
      }
    }
    #pragma unroll
    for (int pp=0;pp<8;++pp){
      unsigned add=(pp&1)?0x10000u:1u;
      unsigned* h=&hist[(pp>>1)<<13];
      atomicAdd(&h[(__float_as_uint(acc[pp].x)&0x7fffffffu)>>18],add);
      atomicAdd(&h[(__float_as_uint(acc[pp].y)&0x7fffffffu)>>18],add);
      atomicAdd(&h[(__float_as_uint(acc[pp].z)&0x7fffffffu)>>18],add);
      atomicAdd(&h[(__float_as_uint(acc[pp].w)&0x7fffffffu)>>18],add);
    }
  }
  __syncthreads();
  for (int i=tid;i<32768;i+=1024){
    unsigned v=hist[i];
    if (v){
      int pair=i>>13, bin=i&8191;
      int pos0=(g<<3)+(pair<<1);
      unsigned lo=v&0xffffu, hi=v>>16;
      if (lo) atomicAdd(&ghist[(pos0<<13)+bin], lo);
      if (hi) atomicAdd(&ghist[((pos0+1)<<13)+bin], hi);
    }
  }
}

// K5b: per-position threshold bin from 8192-bin global histogram.
__global__ void __launch_bounds__(256) k_fth(const unsigned* __restrict__ ghist,
    const int* __restrict__ kkin, unsigned* __restrict__ meta){
  int pos=blockIdx.x, tid=threadIdx.x;
  __shared__ unsigned part[256]; __shared__ unsigned sup[16];
  const unsigned* h=ghist+(pos<<13);
  unsigned s=0;
  for (int k=0;k<32;++k) s+=h[tid*32+k];
  part[tid]=s; __syncthreads();
  if (tid<16){ unsigned t=0; for (int k=0;k<16;++k) t+=part[tid*16+k]; sup[tid]=t; }
  __syncthreads();
  if (tid==0){
    unsigned kk=(unsigned)(*kkin);
    unsigned cum=0; int u=0;
    for (int j=15;j>=0;--j){ if (cum+sup[j]>=kk){ u=j; break; } cum+=sup[j]; }
    int t=u*16;
    for (int j=u*16+15;j>=u*16;--j){ if (cum+part[j]>=kk){ t=j; break; } cum+=part[j]; }
    int b=t*32;
    for (int j=t*32+31;j>=t*32;--j){ if (cum+h[j]>=kk){ b=j; break; } cum+=h[j]; }
    meta[pos*4+0]=(unsigned)b; meta[pos*4+1]=kk-cum; meta[pos*4+2]=h[b];
  }
}

// K5c: shared-sweep masked matvec. grid (32 pos-groups, 8 chunks); 8 pos/block.
__global__ __launch_bounds__(1024) __attribute__((amdgpu_waves_per_eu(4,4)))
void k_fmv(const float* __restrict__ pat,
    const float* __restrict__ pw, const float* __restrict__ xn,
    const unsigned* __restrict__ meta, float* __restrict__ goutr, float* __restrict__ goutrb,
    unsigned* __restrict__ gbits, float* __restrict__ gcon,
    unsigned short* __restrict__ grow, unsigned* __restrict__ gcount, unsigned* __restrict__ gofl){
  __shared__ float pws8[128];
  __shared__ float xnl[4096];
  __shared__ float outr[512];   // 8 pos x 64 rows (this chunk's rows)
  __shared__ float outrb[512];  // threshold-bin sums per row (fallback path)
  __shared__ unsigned lcnt[8];
  int g=blockIdx.x, c=blockIdx.y, tid=threadIdx.x;
  if (tid<128) pws8[tid]=pw[g*128+tid];
  for (int i=tid;i<4096;i+=1024) xnl[i]=xn[(g<<12)+i];
  if (tid<512){ outr[tid]=0.f; outrb[tid]=0.f; }
  if (tid<8) lcnt[tid]=0u;
  __syncthreads();
  unsigned bst[8];
  #pragma unroll
  for (int pp=0;pp<8;++pp) bst[pp]=meta[((g<<3)+pp)*4];
  const float4* patv=(const float4*)pat;
  int lane=tid&63;
  for (int it=0;it<8;++it){
    int f4=(c<<13)+(it<<10)+tid;
    int rowg=f4>>7;             // global row 0..511
    int row=rowg&63;            // local row in this chunk
    int col0=(f4&127)<<2;
    float4 acc[8];
    #pragma unroll
    for (int pp=0;pp<8;++pp) acc[pp]=make_float4(0.f,0.f,0.f,0.f);
    #pragma unroll 4
    for (int p=0;p<16;++p){
      float4 pv=patv[(p<<16)+f4];
      #pragma unroll
      for (int pp=0;pp<8;++pp){
        float w=pws8[(pp<<4)+p];
        acc[pp].x=fmaf(w,pv.x,acc[pp].x); acc[pp].y=fmaf(w,pv.y,acc[pp].y);
        acc[pp].z=fmaf(w,pv.z,acc[pp].z); acc[pp].w=fmaf(w,pv.w,acc[pp].w);
      }
    }
    #pragma unroll
    for (int pp=0;pp<8;++pp){
      float4 xq=*(const float4*)&xnl[(pp<<9)+col0];
      float vv[4]={acc[pp].x,acc[pp].y,acc[pp].z,acc[pp].w};
      float xv[4]={xq.x,xq.y,xq.z,xq.w};
      float lacc=0.f;
      #pragma unroll
      for (int q=0;q<4;++q){
        unsigned bits=__float_as_uint(vv[q])&0x7fffffffu;
        unsigned pfx=bits>>18;
        if (pfx>bst[pp]) lacc=fmaf(vv[q],xv[q],lacc);
        else if (pfx==bst[pp]){
          float con=vv[q]*xv[q];
          atomicAdd(&outrb[(pp<<6)+row], con);
          unsigned idx=atomicAdd(&lcnt[pp],1u);
          if (idx<CCAP){
            int o=((((g<<3)+pp)<<3)+c)*CCAP+idx;
            gbits[o]=bits; gcon[o]=con; grow[o]=(unsigned short)rowg;
          }
        }
      }
      #pragma unroll
      for (int m=32;m>0;m>>=1) lacc+=__shfl_xor(lacc,m,64);
      if (lane==0 && lacc!=0.f) atomicAdd(&outr[(pp<<6)+row], lacc);
    }
  }
  __syncthreads();
  if (tid<512){
    int pp=tid>>6, r=tid&63;
    goutr [((g<<3)+pp)*512+(c<<6)+r]=outr[tid];
    goutrb[((g<<3)+pp)*512+(c<<6)+r]=outrb[tid];
  }
  if (tid<8){
    unsigned n=lcnt[tid];
    gcount[((g<<3)+tid)*8+c]=n;
    if (n>CCAP) gofl[(g<<3)+tid]=1u;
  }
}

// K5d: per-position exact refinement over stashed candidates + apply + residual + LN2.
__global__ void __launch_bounds__(256) k_fref(const float* __restrict__ x,
    const float* __restrict__ goutr, const float* __restrict__ goutrb,
    const unsigned* __restrict__ meta, const unsigned* __restrict__ gcount,
    const unsigned* __restrict__ gofl, const unsigned* __restrict__ gbits,
    const float* __restrict__ gcon, const unsigned short* __restrict__ grow,
    const float* __restrict__ inten, const float* __restrict__ n2g, const float* __restrict__ n2b,
    float* __restrict__ co){
  int pos=blockIdx.x, tid=threadIdx.x;
  __shared__ float outr[512]; __shared__ unsigned rhist[2048]; __shared__ unsigned rpart[128];
  __shared__ unsigned thsh[4]; __shared__ float red[256];
  outr[tid]=goutr[pos*512+tid]; outr[tid+256]=goutr[pos*512+tid+256];
  unsigned bstar=meta[pos*4], rnk=meta[pos*4+1];
  bool ofl = gofl[pos]!=0u;
  if (ofl){
    outr[tid]+=goutrb[pos*512+tid]; outr[tid+256]+=goutrb[pos*512+tid+256];
    __syncthreads();
  } else {
    for (int i=tid;i<2048;i+=256) rhist[i]=0u;
    __syncthreads();
    for (int c=0;c<8;++c){
      unsigned n=gcount[pos*8+c]; if (n>CCAP) n=CCAP;
      const unsigned* cb=gbits+(((pos<<3)+c)*CCAP);
      for (unsigned i=tid;i<n;i+=256) atomicAdd(&rhist[(cb[i]>>7)&0x7ffu],1u);
    }
    __syncthreads();
    if (tid<128){ unsigned t=0;
      #pragma unroll
      for (int k=0;k<16;++k) t+=rhist[tid*16+k];
      rpart[tid]=t; }
    __syncthreads();
    if (tid==0){
      unsigned cum=0; int rp=0;
      for (int j=127;j>=0;--j){ if (cum+rpart[j]>=rnk){ rp=j; break; } cum+=rpart[j]; }
      int sub=rp*16;
      for (int j=rp*16+15;j>=rp*16;--j){ if (cum+rhist[j]>=rnk){ sub=j; break; } cum+=rhist[j]; }
      thsh[0]=(unsigned)sub; thsh[1]=rnk-cum;
    }
    __syncthreads();
    unsigned sub=thsh[0], r2=thsh[1];
    if (tid<128) rhist[tid]=0u;
    __syncthreads();
    for (int c=0;c<8;++c){
      unsigned n=gcount[pos*8+c]; if (n>CCAP) n=CCAP;
      const unsigned* cb=gbits+(((pos<<3)+c)*CCAP);
      for (unsigned i=tid;i<n;i+=256) if (((cb[i]>>7)&0x7ffu)==sub) atomicAdd(&rhist[cb[i]&127u],1u);
    }
    __syncthreads();
    if (tid==0){
      unsigned cum=0; unsigned lo=0;
      for (int j=127;j>=0;--j){ if (cum+rhist[j]>=r2){ lo=(unsigned)j; break; } cum+=rhist[j]; }
      thsh[2]=(bstar<<18)|(sub<<7)|lo;
    }
    __syncthreads();
    unsigned thb=thsh[2];
    for (int c=0;c<8;++c){
      unsigned n=gcount[pos*8+c]; if (n>CCAP) n=CCAP;
      int base=((pos<<3)+c)*CCAP;
      for (unsigned i=tid;i<n;i+=256)
        if (gbits[base+i]>=thb) atomicAdd(&outr[grow[base+i]], gcon[base+i]);
    }
  }
  __syncthreads();
  float it=inten[pos];
  float t0=x[pos*D+tid]+outr[tid]*it;
  float t1=x[pos*D+tid+256]+outr[tid+256]*it;
  red[tid]=t0+t1; __syncthreads();
  for (int st=128;st>0;st>>=1){ if (tid<st) red[tid]+=red[tid+st]; __syncthreads(); }
  float mean=red[0]*(1.f/512.f); __syncthreads();
  float d0=t0-mean, d1=t1-mean;
  red[tid]=d0*d0+d1*d1; __syncthreads();
  for (int st=128;st>0;st>>=1){ if (tid<st) red[tid]+=red[tid+st]; __syncthreads(); }
  float var=red[0]*(1.f/512.f);
  float rstd=rsqrtf(var+1e-5f);
  co[pos*D+tid]=d0*rstd*n2g[tid]+n2b[tid];
  co[pos*D+tid+256]=d1*rstd*n2g[tid+256]+n2b[tid+256];
}

// ---------------- GEMM: RTx64 tile, LDS-staged, prefetch ----------------
template<int ACT, int RES, int RT>
__global__ void __launch_bounds__(256) k_gemm2(const float* __restrict__ A, const float* __restrict__ W,
    const float* __restrict__ bias, const float* __restrict__ res,
    float* __restrict__ C, int K, int N){
  __shared__ float Ast[32][RT+4];
  __shared__ float Ws[32][68];
  const int RPT=RT/8;
  int tid=threadIdx.x;
  int cb=blockIdx.x<<6;
  int s0=blockIdx.y*RT;
  int rid=tid>>5;
  int cid=tid&31;
  int arow=tid>>3, akq=tid&7;
  int wrow=tid>>4, wc4=tid&15;
  bool aload = tid < RT*8;
  float acc[RPT][2];
  #pragma unroll
  for (int r=0;r<RPT;++r){ acc[r][0]=0.f; acc[r][1]=0.f; }
  const float* Aptr = A + (size_t)(s0+arow)*K + (akq<<2);
  const float* Wptr0 = W + (size_t)wrow*N + cb + (wc4<<2);
  const float* Wptr1 = W + (size_t)(wrow+16)*N + cb + (wc4<<2);
  float4 av=make_float4(0.f,0.f,0.f,0.f);
  if (aload) av=*(const float4*)Aptr;
  float4 w0=*(const float4*)Wptr0;
  float4 w1=*(const float4*)Wptr1;
  for (int k0=0;k0<K;k0+=32){
    if (aload){
      Ast[(akq<<2)+0][arow]=av.x; Ast[(akq<<2)+1][arow]=av.y;
      Ast[(akq<<2)+2][arow]=av.z; Ast[(akq<<2)+3][arow]=av.w;
    }
    *(float4*)&Ws[wrow][wc4<<2]=w0;
    *(float4*)&Ws[wrow+16][wc4<<2]=w1;
    __syncthreads();
    if (k0+32<K){
      if (aload) av=*(const float4*)(Aptr + k0+32);
      w0=*(const float4*)(Wptr0 + (size_t)(k0+32)*N);
      w1=*(const float4*)(Wptr1 + (size_t)(k0+32)*N);
    }
    #pragma unroll
    for (int kk=0;kk<32;++kk){
      float b0=Ws[kk][cid], b1=Ws[kk][cid+32];
      if constexpr (RPT==4){
        float4 a4=*(const float4*)&Ast[kk][rid<<2];
        acc[0][0]=fmaf(a4.x,b0,acc[0][0]); acc[0][1]=fmaf(a4.x,b1,acc[0][1]);
        acc[1][0]=fmaf(a4.y,b0,acc[1][0]); acc[1][1]=fmaf(a4.y,b1,acc[1][1]);
        acc[2][0]=fmaf(a4.z,b0,acc[2][0]); acc[2][1]=fmaf(a4.z,b1,acc[2][1]);
        acc[3][0]=fmaf(a4.w,b0,acc[3][0]); acc[3][1]=fmaf(a4.w,b1,acc[3][1]);
      } else {
        float2 a2=*(const float2*)&Ast[kk][rid<<1];
        acc[0][0]=fmaf(a2.x,b0,acc[0][0]); acc[0][1]=fmaf(a2.x,b1,acc[0][1]);
        acc[1][0]=fmaf(a2.y,b0,acc[1][0]); acc[1][1]=fmaf(a2.y,b1,acc[1][1]);
      }
    }
    __syncthreads();
  }
  float bb0=bias[cb+cid], bb1=bias[cb+cid+32];
  #pragma unroll
  for (int r=0;r<RPT;++r){
    int row=s0+rid*RPT+r;
    #pragma unroll
    for (int c=0;c<2;++c){
      int col=cb+cid+(c<<5);
      float v=acc[r][c]+(c?bb1:bb0);
      if (ACT==1) v=gelu_f(v);
      if (ACT==2) v=silu_f(v);
      if (RES) v+=res[(size_t)row*N+col];
      C[(size_t)row*N+col]=v;
    }
  }
}

// gated FFN elementwise
__global__ void __launch_bounds__(256) k_gate(const float* __restrict__ ff, float* __restrict__ gv){
  int idx=blockIdx.x*256+threadIdx.x;
  if (idx<S*2048){
    int s2=idx>>11, m=idx&2047;
    float g=ff[s2*4096+m], v=ff[s2*4096+2048+m];
    gv[idx]=silu_f(g)*v;
  }
}

extern "C" void kernel_launch(void* const* d_in, const int* in_sizes, int n_in,
                              void* d_out, int out_size, void* d_ws, size_t ws_size,
                              hipStream_t stream){
  const float* x   =(const float*)d_in[0];
  const float* pat =(const float*)d_in[1];
  const float* sw1 =(const float*)d_in[2];
  const float* sb1 =(const float*)d_in[3];
  const float* sw2 =(const float*)d_in[4];
  const float* sb2 =(const float*)d_in[5];
  const float* ww1 =(const float*)d_in[6];
  const float* wb1 =(const float*)d_in[7];
  const float* ww2 =(const float*)d_in[8];
  const float* wb2 =(const float*)d_in[9];
  const float* iw1 =(const float*)d_in[10];
  const float* ib1 =(const float*)d_in[11];
  const float* iw2 =(const float*)d_in[12];
  const float* ib2 =(const float*)d_in[13];
  const float* mw1 =(const float*)d_in[14];
  const float* mb1 =(const float*)d_in[15];
  const float* mw2 =(const float*)d_in[16];
  const float* mb2 =(const float*)d_in[17];
  const float* bank=(const float*)d_in[18];
  const float* upw =(const float*)d_in[19];
  const float* upb =(const float*)d_in[20];
  const float* dww =(const float*)d_in[21];
  const float* dwb =(const float*)d_in[22];
  const float* n1g =(const float*)d_in[23];
  const float* n1b =(const float*)d_in[24];
  const float* n2g =(const float*)d_in[25];
  const float* n2b =(const float*)d_in[26];
  float* out=(float*)d_out;

  float* w = (float*)d_ws;
  float* xn     = w;                 // 131072
  float* xr     = xn+131072;         // 131072
  float* meanxr = xr+131072;         // 512
  float* memmean= meanxr+512;        // 512
  float* pwb    = memmean+512;       // 4096
  float* inten  = pwb+4096;          // 256
  float* ctxsel = inten+256;         // 32
  float* ctxint = ctxsel+32;         // 64
  float* mempart= ctxint+64;         // 512
  float* gwb    = mempart+512;       // 64
  float* co     = gwb+64;            // 131072
  float* h1     = co+131072;         // 131072
  float* co2    = h1+131072;         // 131072
  float* ff     = co2+131072;        // 1048576
  float* gv     = ff+1048576;        // 524288
  int*   kkp    = (int*)(gv+524288);          // 4
  unsigned* meta= (unsigned*)(kkp+4);         // 1024
  // zeroed region: ghist (8192x256 u32) + gofl (256 u32)
  unsigned* ghist = (unsigned*)(meta+1024);   // 2097152 u32
  unsigned* gofl  = ghist+2097152;            // 256
  // plain-stored (no memset needed)
  float* goutr  = (float*)(gofl+256);         // 131072 f32
  float* goutrb = goutr+131072;               // 131072 f32
  unsigned* gcount=(unsigned*)(goutrb+131072);// 2048
  unsigned* gbits = gcount+2048;              // 2097152 u32
  float* gcon   = (float*)(gbits+2097152);    // 2097152 f32
  unsigned short* grow = (unsigned short*)(gcon+2097152); // 2097152 u16

  hipMemsetAsync(ghist, 0, (size_t)(2097152+256)*4, stream);

  k_ln_rope<<<S,256,0,stream>>>(x,n1g,n1b,xn,xr);
  k_colmean<<<4,256,0,stream>>>(xr,bank,meanxr,memmean);
  k_fold<<<21,256,0,stream>>>(meanxr,memmean,mw1,mb1,iw1,ib1,sw1,sb1,ww1,wb1,
                              mempart,ctxint,ctxsel,gwb);
  k_kk<<<1,64,0,stream>>>(gwb,ww2,wb2,kkp);
  k_selint<<<S,256,0,stream>>>(xr,ctxsel,ctxint,sw1,sw2,sb2,iw1,iw2,ib2,pwb,inten);
  k_fhist<<<dim3(32,8),1024,0,stream>>>(pat,pwb,ghist);
  k_fth<<<S,256,0,stream>>>(ghist,kkp,(unsigned*)meta);
  k_fmv<<<dim3(32,8),1024,0,stream>>>(pat,pwb,xn,(unsigned*)meta,goutr,goutrb,gbits,gcon,grow,gcount,gofl);
  k_fref<<<S,256,0,stream>>>(x,goutr,goutrb,(unsigned*)meta,gcount,gofl,gbits,gcon,grow,inten,n2g,n2b,co);
  k_gemm2<2,0,16><<<dim3(8,16),256,0,stream>>>(co, mw1, mempart, nullptr, h1, 512, 512);
  k_gemm2<0,1,16><<<dim3(8,16),256,0,stream>>>(h1, mw2, mb2, co, co2, 512, 512);
  k_gemm2<0,0,16><<<dim3(64,16),256,0,stream>>>(co2, upw, upb, nullptr, ff, 512, 4096);
  k_gate<<<2048,256,0,stream>>>(ff,gv);
  k_gemm2<0,1,16><<<dim3(8,16),256,0,stream>>>(gv, dww, dwb, co2, out, 2048, 512);
}

// Round 10
// 462.138 us; speedup vs baseline: 2.0278x; 1.0105x over previous
//
#include <hip/hip_runtime.h>
#include <math.h>

#define S 256
#define D 512
#define P 16
#define NIJ (D*D)
#define CCAP 1024   // per-(pos,chunk) candidate stash capacity

__device__ __forceinline__ float gelu_f(float x){ return 0.5f*x*(1.f+erff(x*0.70710678118654752f)); }
__device__ __forceinline__ float silu_f(float x){ return x/(1.f+expf(-x)); }
__device__ __forceinline__ float sigm_f(float x){ return 1.f/(1.f+expf(-x)); }

__device__ __forceinline__ float4 gate4(const float* p){
  float4 g=*(const float4*)p; float4 v=*(const float4*)(p+2048);
  return make_float4(silu_f(g.x)*v.x, silu_f(g.y)*v.y, silu_f(g.z)*v.z, silu_f(g.w)*v.w);
}

// K1: LayerNorm + RoPE per row
__global__ void __launch_bounds__(256) k_ln_rope(const float* __restrict__ x,
    const float* __restrict__ g, const float* __restrict__ b,
    float* __restrict__ xn, float* __restrict__ xr){
  int s2 = blockIdx.x, tid = threadIdx.x;
  __shared__ float red[256];
  __shared__ float xnl[512];
  const float* xrow = x + s2*D;
  float v0 = xrow[tid], v1 = xrow[tid+256];
  red[tid] = v0+v1; __syncthreads();
  for (int st=128; st>0; st>>=1){ if (tid<st) red[tid]+=red[tid+st]; __syncthreads(); }
  float mean = red[0]*(1.f/512.f); __syncthreads();
  float d0=v0-mean, d1=v1-mean;
  red[tid]=d0*d0+d1*d1; __syncthreads();
  for (int st=128; st>0; st>>=1){ if (tid<st) red[tid]+=red[tid+st]; __syncthreads(); }
  float var = red[0]*(1.f/512.f);
  float rstd = rsqrtf(var+1e-5f);
  float a0 = d0*rstd*g[tid]+b[tid];
  float a1 = d1*rstd*g[tid+256]+b[tid+256];
  xn[s2*D+tid]=a0; xn[s2*D+tid+256]=a1;
  xnl[tid]=a0; xnl[tid+256]=a1;
  __syncthreads();
  int j = tid;
  float e = (float)(2*j)*(1.f/512.f);
  float inv = 1.f/powf(10000.f, e);
  float ang = (float)s2 * inv;
  float c = cosf(ang), sn = sinf(ang);
  float p0 = xnl[2*j], p1 = xnl[2*j+1];
  xr[s2*D+2*j]   = p0*c - p1*sn;
  xr[s2*D+2*j+1] = p1*c + p0*sn;
}

// K2: column means
__global__ void __launch_bounds__(256) k_colmean(const float* __restrict__ xr,
    const float* __restrict__ bank, float* __restrict__ meanxr, float* __restrict__ memmean){
  int tid=threadIdx.x;
  if (blockIdx.x<2){
    int d2 = blockIdx.x*256+tid; float acc=0.f;
    for (int s2=0;s2<S;++s2) acc += xr[s2*D+d2];
    meanxr[d2]=acc*(1.f/256.f);
  } else {
    int d2=(blockIdx.x-2)*256+tid; float acc=0.f;
    for (int r=0;r<512;++r) acc += bank[r*D+d2];
    memmean[d2]=acc*(1.f/512.f);
  }
}

// K3a: parallel fold GEMVs. 21 blocks x 32 outputs.
__global__ void __launch_bounds__(256) k_fold(const float* __restrict__ meanxr,
    const float* __restrict__ memmean,
    const float* __restrict__ mw1, const float* __restrict__ mb1,
    const float* __restrict__ iw1, const float* __restrict__ ib1,
    const float* __restrict__ sw1, const float* __restrict__ sb1,
    const float* __restrict__ ww1, const float* __restrict__ wb1,
    float* __restrict__ mempart, float* __restrict__ ctxint,
    float* __restrict__ ctxsel, float* __restrict__ gw){
  __shared__ float vec[512];
  __shared__ float red[256];
  int b=blockIdx.x, tid=threadIdx.x;
  int seg, obase; const float* W; const float* bias; float* outp; int N; int rowoff;
  if (b<16){ seg=0; obase=b*32; W=mw1; bias=mb1; outp=mempart; N=512; rowoff=512; }
  else if (b<18){ seg=1; obase=(b-16)*32; W=iw1; bias=ib1; outp=ctxint; N=64; rowoff=512; }
  else if (b<19){ seg=2; obase=0; W=sw1; bias=sb1; outp=ctxsel; N=32; rowoff=512; }
  else { seg=3; obase=(b-19)*32; W=ww1; bias=wb1; outp=gw; N=64; rowoff=0; }
  const float* v=(seg==0)?memmean:meanxr;
  vec[tid]=v[tid]; vec[tid+256]=v[tid+256];
  __syncthreads();
  int ol=tid&31, ch=tid>>5;
  float a=0.f;
  int d0=ch*64;
  for (int d=d0; d<d0+64; ++d) a=fmaf(vec[d], W[(size_t)(rowoff+d)*N+obase+ol], a);
  red[tid]=a; __syncthreads();
  if (tid<32){
    float s=bias[obase+tid];
    #pragma unroll
    for (int k=0;k<8;++k) s+=red[k*32+tid];
    if (seg==3) s=gelu_f(s);
    outp[obase+tid]=s;
  }
}

// K3b: window head -> kk
__global__ void k_kk(const float* __restrict__ gw, const float* __restrict__ ww2,
    const float* __restrict__ wb2, int* __restrict__ kkout){
  int tid=threadIdx.x;  // 64
  float a=gw[tid]*ww2[tid];
  #pragma unroll
  for (int m=32;m>0;m>>=1) a+=__shfl_xor(a,m,64);
  if (tid==0){
    float win=sigm_f(a+wb2[0])*3840.f+256.f;
    float asp=0.1f*(win*(1.f/4096.f));
    float t=262144.f*asp;
    int kk=(int)t; if (kk<1) kk=1;
    *kkout=kk;
  }
}

// K4: per-position selection MLP (softmax pw) + intensity. 2-way K-split dots.
__global__ void __launch_bounds__(256) k_selint(const float* __restrict__ xr,
    const float* __restrict__ ctxsel, const float* __restrict__ ctxint,
    const float* __restrict__ sw1, const float* __restrict__ sw2, const float* __restrict__ sb2,
    const float* __restrict__ iw1, const float* __restrict__ iw2, const float* __restrict__ ib2,
    float* __restrict__ pw, float* __restrict__ inten){
  int s2=blockIdx.x, tid=threadIdx.x;
  __shared__ float xl[512]; __shared__ float red[192];
  __shared__ float h1[32], h2[64], lg[16];
  xl[tid]=xr[s2*D+tid]; xl[tid+256]=xr[s2*D+tid+256];
  __syncthreads();
  if (tid<192){
    int half=(tid>=96)?1:0; int o=tid-96*half;
    int d0=half<<8;
    float a=0.f;
    if (o<32){
      const float* Wp=sw1+o;
      #pragma unroll 4
      for (int d=d0; d<d0+256; ++d) a=fmaf(xl[d], Wp[d*32], a);
    } else {
      const float* Wp=iw1+(o-32);
      #pragma unroll 4
      for (int d=d0; d<d0+256; ++d) a=fmaf(xl[d], Wp[d*64], a);
    }
    red[tid]=a;
  }
  __syncthreads();
  if (tid<96){
    float a=red[tid]+red[tid+96];
    if (tid<32) h1[tid]=gelu_f(a+ctxsel[tid]);
    else h2[tid-32]=gelu_f(a+ctxint[tid-32]);
  }
  __syncthreads();
  if (tid<16){ float a=sb2[tid]; for (int h=0;h<32;++h) a=fmaf(h1[h], sw2[h*16+tid], a); lg[tid]=a; }
  __syncthreads();
  if (tid==0){
    float m=lg[0]; for (int p2=1;p2<16;++p2) m=fmaxf(m,lg[p2]);
    float sm=0.f; float e[16];
    for (int p2=0;p2<16;++p2){ e[p2]=expf(lg[p2]-m); sm+=e[p2]; }
    float r=1.f/sm;
    for (int p2=0;p2<16;++p2) pw[s2*16+p2]=e[p2]*r;
  }
  if (tid==64){ float a=ib2[0]; for (int h=0;h<64;++h) a=fmaf(h2[h], iw2[h], a); inten[s2]=sigm_f(a); }
}

// K5a: shared-sweep histogram. grid (32 pos-groups, 8 chunks); 8 pos/block.
__global__ __launch_bounds__(1024) __attribute__((amdgpu_waves_per_eu(4,4)))
void k_fhist(const float* __restrict__ pat,
    const float* __restrict__ pw, unsigned* __restrict__ ghist){
  __shared__ unsigned hist[4*8192];   // 128KB
  __shared__ float pws8[128];
  int g=blockIdx.x, c=blockIdx.y, tid=threadIdx.x;
  if (tid<128) pws8[tid]=pw[g*128+tid];
  for (int i=tid;i<32768;i+=1024) hist[i]=0u;
  __syncthreads();
  const float4* patv=(const float4*)pat;
  for (int it=0;it<8;++it){
    int f4=(c<<13)+(it<<10)+tid;
    float4 acc[8];
    #pragma unroll
    for (int pp=0;pp<8;++pp) acc[pp]=make_float4(0.f,0.f,0.f,0.f);
    #pragma unroll 4
    for (int p=0;p<16;++p){
      float4 pv=patv[(p<<16)+f4];
      #pragma unroll
      for (int pp=0;pp<8;++pp){
        float w=pws8[(pp<<4)+p];
        acc[pp].x=fmaf(w,pv.x,acc[pp].x); acc[pp].y=fmaf(w,pv.y,acc[pp].y);
        acc[pp].z=fmaf(w,pv.z,acc[pp].z); acc[pp].w=fmaf(w,pv.w,acc[pp].w);
      }
    }
    #pragma unroll
    for (int pp=0;pp<8;++pp){
      unsigned add=(pp&1)?0x10000u:1u;
      unsigned* h=&hist[(pp>>1)<<13];
      atomicAdd(&h[(__float_as_uint(acc[pp].x)&0x7fffffffu)>>18],add);
      atomicAdd(&h[(__float_as_uint(acc[pp].y)&0x7fffffffu)>>18],add);
      atomicAdd(&h[(__float_as_uint(acc[pp].z)&0x7fffffffu)>>18],add);
      atomicAdd(&h[(__float_as_uint(acc[pp].w)&0x7fffffffu)>>18],add);
    }
  }
  __syncthreads();
  for (int i=tid;i<32768;i+=1024){
    unsigned v=hist[i];
    if (v){
      int pair=i>>13, bin=i&8191;
      int pos0=(g<<3)+(pair<<1);
      unsigned lo=v&0xffffu, hi=v>>16;
      if (lo) atomicAdd(&ghist[(pos0<<13)+bin], lo);
      if (hi) atomicAdd(&ghist[((pos0+1)<<13)+bin], hi);
    }
  }
}

// K5b: per-position threshold bin from 8192-bin global histogram.
__global__ void __launch_bounds__(256) k_fth(const unsigned* __restrict__ ghist,
    const int* __restrict__ kkin, unsigned* __restrict__ meta){
  int pos=blockIdx.x, tid=threadIdx.x;
  __shared__ unsigned part[256]; __shared__ unsigned sup[16];
  const unsigned* h=ghist+(pos<<13);
  unsigned s=0;
  for (int k=0;k<32;++k) s+=h[tid*32+k];
  part[tid]=s; __syncthreads();
  if (tid<16){ unsigned t=0; for (int k=0;k<16;++k) t+=part[tid*16+k]; sup[tid]=t; }
  __syncthreads();
  if (tid==0){
    unsigned kk=(unsigned)(*kkin);
    unsigned cum=0; int u=0;
    for (int j=15;j>=0;--j){ if (cum+sup[j]>=kk){ u=j; break; } cum+=sup[j]; }
    int t=u*16;
    for (int j=u*16+15;j>=u*16;--j){ if (cum+part[j]>=kk){ t=j; break; } cum+=part[j]; }
    int b=t*32;
    for (int j=t*32+31;j>=t*32;--j){ if (cum+h[j]>=kk){ b=j; break; } cum+=h[j]; }
    meta[pos*4+0]=(unsigned)b; meta[pos*4+1]=kk-cum; meta[pos*4+2]=h[b];
  }
}

// K5c: shared-sweep masked matvec. grid (32 pos-groups, 8 chunks); 8 pos/block.
__global__ __launch_bounds__(1024) __attribute__((amdgpu_waves_per_eu(4,4)))
void k_fmv(const float* __restrict__ pat,
    const float* __restrict__ pw, const float* __restrict__ xn,
    const unsigned* __restrict__ meta, float* __restrict__ goutr, float* __restrict__ goutrb,
    unsigned* __restrict__ gbits, float* __restrict__ gcon,
    unsigned short* __restrict__ grow, unsigned* __restrict__ gcount, unsigned* __restrict__ gofl){
  __shared__ float pws8[128];
  __shared__ float xnl[4096];
  __shared__ float outr[512];
  __shared__ float outrb[512];
  __shared__ unsigned lcnt[8];
  int g=blockIdx.x, c=blockIdx.y, tid=threadIdx.x;
  if (tid<128) pws8[tid]=pw[g*128+tid];
  for (int i=tid;i<4096;i+=1024) xnl[i]=xn[(g<<12)+i];
  if (tid<512){ outr[tid]=0.f; outrb[tid]=0.f; }
  if (tid<8) lcnt[tid]=0u;
  __syncthreads();
  unsigned bst[8];
  #pragma unroll
  for (int pp=0;pp<8;++pp) bst[pp]=meta[((g<<3)+pp)*4];
  const float4* patv=(const float4*)pat;
  int lane=tid&63;
  for (int it=0;it<8;++it){
    int f4=(c<<13)+(it<<10)+tid;
    int rowg=f4>>7;
    int row=rowg&63;
    int col0=(f4&127)<<2;
    float4 acc[8];
    #pragma unroll
    for (int pp=0;pp<8;++pp) acc[pp]=make_float4(0.f,0.f,0.f,0.f);
    #pragma unroll 4
    for (int p=0;p<16;++p){
      float4 pv=patv[(p<<16)+f4];
      #pragma unroll
      for (int pp=0;pp<8;++pp){
        float w=pws8[(pp<<4)+p];
        acc[pp].x=fmaf(w,pv.x,acc[pp].x); acc[pp].y=fmaf(w,pv.y,acc[pp].y);
        acc[pp].z=fmaf(w,pv.z,acc[pp].z); acc[pp].w=fmaf(w,pv.w,acc[pp].w);
      }
    }
    #pragma unroll
    for (int pp=0;pp<8;++pp){
      float4 xq=*(const float4*)&xnl[(pp<<9)+col0];
      float vv[4]={acc[pp].x,acc[pp].y,acc[pp].z,acc[pp].w};
      float xv[4]={xq.x,xq.y,xq.z,xq.w};
      float lacc=0.f;
      #pragma unroll
      for (int q=0;q<4;++q){
        unsigned bits=__float_as_uint(vv[q])&0x7fffffffu;
        unsigned pfx=bits>>18;
        if (pfx>bst[pp]) lacc=fmaf(vv[q],xv[q],lacc);
        else if (pfx==bst[pp]){
          float con=vv[q]*xv[q];
          atomicAdd(&outrb[(pp<<6)+row], con);
          unsigned idx=atomicAdd(&lcnt[pp],1u);
          if (idx<CCAP){
            int o=((((g<<3)+pp)<<3)+c)*CCAP+idx;
            gbits[o]=bits; gcon[o]=con; grow[o]=(unsigned short)rowg;
          }
        }
      }
      #pragma unroll
      for (int m=32;m>0;m>>=1) lacc+=__shfl_xor(lacc,m,64);
      if (lane==0 && lacc!=0.f) atomicAdd(&outr[(pp<<6)+row], lacc);
    }
  }
  __syncthreads();
  if (tid<512){
    int pp=tid>>6, r=tid&63;
    goutr [((g<<3)+pp)*512+(c<<6)+r]=outr[tid];
    goutrb[((g<<3)+pp)*512+(c<<6)+r]=outrb[tid];
  }
  if (tid<8){
    unsigned n=lcnt[tid];
    gcount[((g<<3)+tid)*8+c]=n;
    if (n>CCAP) gofl[(g<<3)+tid]=1u;
  }
}

// K5d: per-position exact refinement over stashed candidates + apply + residual + LN2.
__global__ void __launch_bounds__(256) k_fref(const float* __restrict__ x,
    const float* __restrict__ goutr, const float* __restrict__ goutrb,
    const unsigned* __restrict__ meta, const unsigned* __restrict__ gcount,
    const unsigned* __restrict__ gofl, const unsigned* __restrict__ gbits,
    const float* __restrict__ gcon, const unsigned short* __restrict__ grow,
    const float* __restrict__ inten, const float* __restrict__ n2g, const float* __restrict__ n2b,
    float* __restrict__ co){
  int pos=blockIdx.x, tid=threadIdx.x;
  __shared__ float outr[512]; __shared__ unsigned rhist[2048]; __shared__ unsigned rpart[128];
  __shared__ unsigned thsh[4]; __shared__ float red[256];
  outr[tid]=goutr[pos*512+tid]; outr[tid+256]=goutr[pos*512+tid+256];
  unsigned bstar=meta[pos*4], rnk=meta[pos*4+1];
  bool ofl = gofl[pos]!=0u;
  if (ofl){
    outr[tid]+=goutrb[pos*512+tid]; outr[tid+256]+=goutrb[pos*512+tid+256];
    __syncthreads();
  } else {
    for (int i=tid;i<2048;i+=256) rhist[i]=0u;
    __syncthreads();
    for (int c=0;c<8;++c){
      unsigned n=gcount[pos*8+c]; if (n>CCAP) n=CCAP;
      const unsigned* cb=gbits+(((pos<<3)+c)*CCAP);
      for (unsigned i=tid;i<n;i+=256) atomicAdd(&rhist[(cb[i]>>7)&0x7ffu],1u);
    }
    __syncthreads();
    if (tid<128){ unsigned t=0;
      #pragma unroll
      for (int k=0;k<16;++k) t+=rhist[tid*16+k];
      rpart[tid]=t; }
    __syncthreads();
    if (tid==0){
      unsigned cum=0; int rp=0;
      for (int j=127;j>=0;--j){ if (cum+rpart[j]>=rnk){ rp=j; break; } cum+=rpart[j]; }
      int sub=rp*16;
      for (int j=rp*16+15;j>=rp*16;--j){ if (cum+rhist[j]>=rnk){ sub=j; break; } cum+=rhist[j]; }
      thsh[0]=(unsigned)sub; thsh[1]=rnk-cum;
    }
    __syncthreads();
    unsigned sub=thsh[0], r2=thsh[1];
    if (tid<128) rhist[tid]=0u;
    __syncthreads();
    for (int c=0;c<8;++c){
      unsigned n=gcount[pos*8+c]; if (n>CCAP) n=CCAP;
      const unsigned* cb=gbits+(((pos<<3)+c)*CCAP);
      for (unsigned i=tid;i<n;i+=256) if (((cb[i]>>7)&0x7ffu)==sub) atomicAdd(&rhist[cb[i]&127u],1u);
    }
    __syncthreads();
    if (tid==0){
      unsigned cum=0; unsigned lo=0;
      for (int j=127;j>=0;--j){ if (cum+rhist[j]>=r2){ lo=(unsigned)j; break; } cum+=rhist[j]; }
      thsh[2]=(bstar<<18)|(sub<<7)|lo;
    }
    __syncthreads();
    unsigned thb=thsh[2];
    for (int c=0;c<8;++c){
      unsigned n=gcount[pos*8+c]; if (n>CCAP) n=CCAP;
      int base=((pos<<3)+c)*CCAP;
      for (unsigned i=tid;i<n;i+=256)
        if (gbits[base+i]>=thb) atomicAdd(&outr[grow[base+i]], gcon[base+i]);
    }
  }
  __syncthreads();
  float it=inten[pos];
  float t0=x[pos*D+tid]+outr[tid]*it;
  float t1=x[pos*D+tid+256]+outr[tid+256]*it;
  red[tid]=t0+t1; __syncthreads();
  for (int st=128;st>0;st>>=1){ if (tid<st) red[tid]+=red[tid+st]; __syncthreads(); }
  float mean=red[0]*(1.f/512.f); __syncthreads();
  float d0=t0-mean, d1=t1-mean;
  red[tid]=d0*d0+d1*d1; __syncthreads();
  for (int st=128;st>0;st>>=1){ if (tid<st) red[tid]+=red[tid+st]; __syncthreads(); }
  float var=red[0]*(1.f/512.f);
  float rstd=rsqrtf(var+1e-5f);
  co[pos*D+tid]=d0*rstd*n2g[tid]+n2b[tid];
  co[pos*D+tid+256]=d1*rstd*n2g[tid+256]+n2b[tid+256];
}

// ---------------- GEMM: RTx64 tile, LDS-staged, prefetch; optional gated-A ----------------
template<int ACT, int RES, int RT, int GATEA>
__global__ void __launch_bounds__(256) k_gemm2(const float* __restrict__ A, const float* __restrict__ W,
    const float* __restrict__ bias, const float* __restrict__ res,
    float* __restrict__ C, int K, int N){
  __shared__ float Ast[32][RT+4];
  __shared__ float Ws[32][68];
  const int RPT=RT/8;
  int tid=threadIdx.x;
  int cb=blockIdx.x<<6;
  int s0=blockIdx.y*RT;
  int rid=tid>>5;
  int cid=tid&31;
  int arow=tid>>3, akq=tid&7;
  int wrow=tid>>4, wc4=tid&15;
  bool aload = tid < RT*8;
  float acc[RPT][2];
  #pragma unroll
  for (int r=0;r<RPT;++r){ acc[r][0]=0.f; acc[r][1]=0.f; }
  const int LDA = GATEA ? 4096 : K;
  const float* Aptr = A + (size_t)(s0+arow)*LDA + (akq<<2);
  const float* Wptr0 = W + (size_t)wrow*N + cb + (wc4<<2);
  const float* Wptr1 = W + (size_t)(wrow+16)*N + cb + (wc4<<2);
  float4 av=make_float4(0.f,0.f,0.f,0.f);
  if (aload){ if (GATEA) av=gate4(Aptr); else av=*(const float4*)Aptr; }
  float4 w0=*(const float4*)Wptr0;
  float4 w1=*(const float4*)Wptr1;
  for (int k0=0;k0<K;k0+=32){
    if (aload){
      Ast[(akq<<2)+0][arow]=av.x; Ast[(akq<<2)+1][arow]=av.y;
      Ast[(akq<<2)+2][arow]=av.z; Ast[(akq<<2)+3][arow]=av.w;
    }
    *(float4*)&Ws[wrow][wc4<<2]=w0;
    *(float4*)&Ws[wrow+16][wc4<<2]=w1;
    __syncthreads();
    if (k0+32<K){
      if (aload){ if (GATEA) av=gate4(Aptr+k0+32); else av=*(const float4*)(Aptr+k0+32); }
      w0=*(const float4*)(Wptr0 + (size_t)(k0+32)*N);
      w1=*(const float4*)(Wptr1 + (size_t)(k0+32)*N);
    }
    #pragma unroll
    for (int kk=0;kk<32;++kk){
      float b0=Ws[kk][cid], b1=Ws[kk][cid+32];
      if constexpr (RPT==4){
        float4 a4=*(const float4*)&Ast[kk][rid<<2];
        acc[0][0]=fmaf(a4.x,b0,acc[0][0]); acc[0][1]=fmaf(a4.x,b1,acc[0][1]);
        acc[1][0]=fmaf(a4.y,b0,acc[1][0]); acc[1][1]=fmaf(a4.y,b1,acc[1][1]);
        acc[2][0]=fmaf(a4.z,b0,acc[2][0]); acc[2][1]=fmaf(a4.z,b1,acc[2][1]);
        acc[3][0]=fmaf(a4.w,b0,acc[3][0]); acc[3][1]=fmaf(a4.w,b1,acc[3][1]);
      } else {
        float2 a2=*(const float2*)&Ast[kk][rid<<1];
        acc[0][0]=fmaf(a2.x,b0,acc[0][0]); acc[0][1]=fmaf(a2.x,b1,acc[0][1]);
        acc[1][0]=fmaf(a2.y,b0,acc[1][0]); acc[1][1]=fmaf(a2.y,b1,acc[1][1]);
      }
    }
    __syncthreads();
  }
  float bb0=bias[cb+cid], bb1=bias[cb+cid+32];
  #pragma unroll
  for (int r=0;r<RPT;++r){
    int row=s0+rid*RPT+r;
    #pragma unroll
    for (int c=0;c<2;++c){
      int col=cb+cid+(c<<5);
      float v=acc[r][c]+(c?bb1:bb0);
      if (ACT==1) v=gelu_f(v);
      if (ACT==2) v=silu_f(v);
      if (RES) v+=res[(size_t)row*N+col];
      C[(size_t)row*N+col]=v;
    }
  }
}

// ---------------- GEMM64: 64x64 tile, 4x4 per thread ----------------
template<int ACT, int RES>
__global__ void __launch_bounds__(256) k_gemm64(const float* __restrict__ A, const float* __restrict__ W,
    const float* __restrict__ bias, const float* __restrict__ res,
    float* __restrict__ C, int K, int N){
  __shared__ float Ast[32][68];
  __shared__ float Ws[32][68];
  int tid=threadIdx.x;
  int cb=blockIdx.x<<6;
  int s0=blockIdx.y<<6;
  int rid=tid>>4, cid=tid&15;
  int ar=tid>>3, akq=tid&7;
  int wrow=tid>>4, wc4=tid&15;
  float acc[4][4];
  #pragma unroll
  for (int i=0;i<4;++i){
    #pragma unroll
    for (int j=0;j<4;++j) acc[i][j]=0.f;
  }
  const float* Ap0 = A + (size_t)(s0+ar)*K + (akq<<2);
  const float* Ap1 = A + (size_t)(s0+ar+32)*K + (akq<<2);
  const float* Wp0 = W + (size_t)wrow*N + cb + (wc4<<2);
  const float* Wp1 = W + (size_t)(wrow+16)*N + cb + (wc4<<2);
  float4 a0=*(const float4*)Ap0, a1=*(const float4*)Ap1;
  float4 w0=*(const float4*)Wp0, w1=*(const float4*)Wp1;
  for (int k0=0;k0<K;k0+=32){
    Ast[(akq<<2)+0][ar]=a0.x; Ast[(akq<<2)+1][ar]=a0.y;
    Ast[(akq<<2)+2][ar]=a0.z; Ast[(akq<<2)+3][ar]=a0.w;
    Ast[(akq<<2)+0][ar+32]=a1.x; Ast[(akq<<2)+1][ar+32]=a1.y;
    Ast[(akq<<2)+2][ar+32]=a1.z; Ast[(akq<<2)+3][ar+32]=a1.w;
    *(float4*)&Ws[wrow][wc4<<2]=w0;
    *(float4*)&Ws[wrow+16][wc4<<2]=w1;
    __syncthreads();
    if (k0+32<K){
      a0=*(const float4*)(Ap0+k0+32);
      a1=*(const float4*)(Ap1+k0+32);
      w0=*(const float4*)(Wp0 + (size_t)(k0+32)*N);
      w1=*(const float4*)(Wp1 + (size_t)(k0+32)*N);
    }
    #pragma unroll
    for (int kk=0;kk<32;++kk){
      float4 a4=*(const float4*)&Ast[kk][rid<<2];
      float b0=Ws[kk][cid], b1=Ws[kk][cid+16], b2=Ws[kk][cid+32], b3=Ws[kk][cid+48];
      acc[0][0]=fmaf(a4.x,b0,acc[0][0]); acc[0][1]=fmaf(a4.x,b1,acc[0][1]); acc[0][2]=fmaf(a4.x,b2,acc[0][2]); acc[0][3]=fmaf(a4.x,b3,acc[0][3]);
      acc[1][0]=fmaf(a4.y,b0,acc[1][0]); acc[1][1]=fmaf(a4.y,b1,acc[1][1]); acc[1][2]=fmaf(a4.y,b2,acc[1][2]); acc[1][3]=fmaf(a4.y,b3,acc[1][3]);
      acc[2][0]=fmaf(a4.z,b0,acc[2][0]); acc[2][1]=fmaf(a4.z,b1,acc[2][1]); acc[2][2]=fmaf(a4.z,b2,acc[2][2]); acc[2][3]=fmaf(a4.z,b3,acc[2][3]);
      acc[3][0]=fmaf(a4.w,b0,acc[3][0]); acc[3][1]=fmaf(a4.w,b1,acc[3][1]); acc[3][2]=fmaf(a4.w,b2,acc[3][2]); acc[3][3]=fmaf(a4.w,b3,acc[3][3]);
    }
    __syncthreads();
  }
  #pragma unroll
  for (int i=0;i<4;++i){
    int row=s0+(rid<<2)+i;
    #pragma unroll
    for (int j=0;j<4;++j){
      int col=cb+cid+(j<<4);
      float v=acc[i][j]+bias[col];
      if (ACT==1) v=gelu_f(v);
      if (ACT==2) v=silu_f(v);
      if (RES) v+=res[(size_t)row*N+col];
      C[(size_t)row*N+col]=v;
    }
  }
}

extern "C" void kernel_launch(void* const* d_in, const int* in_sizes, int n_in,
                              void* d_out, int out_size, void* d_ws, size_t ws_size,
                              hipStream_t stream){
  const float* x   =(const float*)d_in[0];
  const float* pat =(const float*)d_in[1];
  const float* sw1 =(const float*)d_in[2];
  const float* sb1 =(const float*)d_in[3];
  const float* sw2 =(const float*)d_in[4];
  const float* sb2 =(const float*)d_in[5];
  const float* ww1 =(const float*)d_in[6];
  const float* wb1 =(const float*)d_in[7];
  const float* ww2 =(const float*)d_in[8];
  const float* wb2 =(const float*)d_in[9];
  const float* iw1 =(const float*)d_in[10];
  const float* ib1 =(const float*)d_in[11];
  const float* iw2 =(const float*)d_in[12];
  const float* ib2 =(const float*)d_in[13];
  const float* mw1 =(const float*)d_in[14];
  const float* mb1 =(const float*)d_in[15];
  const float* mw2 =(const float*)d_in[16];
  const float* mb2 =(const float*)d_in[17];
  const float* bank=(const float*)d_in[18];
  const float* upw =(const float*)d_in[19];
  const float* upb =(const float*)d_in[20];
  const float* dww =(const float*)d_in[21];
  const float* dwb =(const float*)d_in[22];
  const float* n1g =(const float*)d_in[23];
  const float* n1b =(const float*)d_in[24];
  const float* n2g =(const float*)d_in[25];
  const float* n2b =(const float*)d_in[26];
  float* out=(float*)d_out;

  float* w = (float*)d_ws;
  float* xn     = w;                 // 131072
  float* xr     = xn+131072;         // 131072
  float* meanxr = xr+131072;         // 512
  float* memmean= meanxr+512;        // 512
  float* pwb    = memmean+512;       // 4096
  float* inten  = pwb+4096;          // 256
  float* ctxsel = inten+256;         // 32
  float* ctxint = ctxsel+32;         // 64
  float* mempart= ctxint+64;         // 512
  float* gwb    = mempart+512;       // 64
  float* co     = gwb+64;            // 131072
  float* h1     = co+131072;         // 131072
  float* co2    = h1+131072;         // 131072
  float* ff     = co2+131072;        // 1048576
  float* gv     = ff+1048576;        // 524288 (unused, kept for layout)
  int*   kkp    = (int*)(gv+524288);          // 4
  unsigned* meta= (unsigned*)(kkp+4);         // 1024
  unsigned* ghist = (unsigned*)(meta+1024);   // 2097152 u32 (zeroed)
  unsigned* gofl  = ghist+2097152;            // 256 (zeroed)
  float* goutr  = (float*)(gofl+256);         // 131072 f32
  float* goutrb = goutr+131072;               // 131072 f32
  unsigned* gcount=(unsigned*)(goutrb+131072);// 2048
  unsigned* gbits = gcount+2048;              // 2097152 u32
  float* gcon   = (float*)(gbits+2097152);    // 2097152 f32
  unsigned short* grow = (unsigned short*)(gcon+2097152); // 2097152 u16

  hipMemsetAsync(ghist, 0, (size_t)(2097152+256)*4, stream);

  k_ln_rope<<<S,256,0,stream>>>(x,n1g,n1b,xn,xr);
  k_colmean<<<4,256,0,stream>>>(xr,bank,meanxr,memmean);
  k_fold<<<21,256,0,stream>>>(meanxr,memmean,mw1,mb1,iw1,ib1,sw1,sb1,ww1,wb1,
                              mempart,ctxint,ctxsel,gwb);
  k_kk<<<1,64,0,stream>>>(gwb,ww2,wb2,kkp);
  k_selint<<<S,256,0,stream>>>(xr,ctxsel,ctxint,sw1,sw2,sb2,iw1,iw2,ib2,pwb,inten);
  k_fhist<<<dim3(32,8),1024,0,stream>>>(pat,pwb,ghist);
  k_fth<<<S,256,0,stream>>>(ghist,kkp,(unsigned*)meta);
  k_fmv<<<dim3(32,8),1024,0,stream>>>(pat,pwb,xn,(unsigned*)meta,goutr,goutrb,gbits,gcon,grow,gcount,gofl);
  k_fref<<<S,256,0,stream>>>(x,goutr,goutrb,(unsigned*)meta,gcount,gofl,gbits,gcon,grow,inten,n2g,n2b,co);
  k_gemm2<2,0,16,0><<<dim3(8,16),256,0,stream>>>(co, mw1, mempart, nullptr, h1, 512, 512);
  k_gemm2<0,1,16,0><<<dim3(8,16),256,0,stream>>>(h1, mw2, mb2, co, co2, 512, 512);
  k_gemm64<0,0><<<dim3(64,4),256,0,stream>>>(co2, upw, upb, nullptr, ff, 512, 4096);
  k_gemm2<0,1,16,1><<<dim3(8,16),256,0,stream>>>(ff, dww, dwb, co2, out, 2048, 512);
}

// Round 11
// 414.608 us; speedup vs baseline: 2.2603x; 1.1146x over previous
//
#include <hip/hip_runtime.h>
#include <math.h>

#define S 256
#define D 512
#define P 16
#define NIJ (D*D)
#define CCAP 1024   // per-(pos,chunk) candidate stash capacity

__device__ __forceinline__ float gelu_f(float x){ return 0.5f*x*(1.f+erff(x*0.70710678118654752f)); }
__device__ __forceinline__ float silu_f(float x){ return x/(1.f+expf(-x)); }
__device__ __forceinline__ float sigm_f(float x){ return 1.f/(1.f+expf(-x)); }

__device__ __forceinline__ float4 gate4(const float* p){
  float4 g=*(const float4*)p; float4 v=*(const float4*)(p+2048);
  return make_float4(silu_f(g.x)*v.x, silu_f(g.y)*v.y, silu_f(g.z)*v.z, silu_f(g.w)*v.w);
}
__device__ __forceinline__ float4 silu4(const float* p){
  float4 g=*(const float4*)p;
  return make_float4(silu_f(g.x), silu_f(g.y), silu_f(g.z), silu_f(g.w));
}

// K1: LayerNorm + RoPE per row
__global__ void __launch_bounds__(256) k_ln_rope(const float* __restrict__ x,
    const float* __restrict__ g, const float* __restrict__ b,
    float* __restrict__ xn, float* __restrict__ xr){
  int s2 = blockIdx.x, tid = threadIdx.x;
  __shared__ float red[256];
  __shared__ float xnl[512];
  const float* xrow = x + s2*D;
  float v0 = xrow[tid], v1 = xrow[tid+256];
  red[tid] = v0+v1; __syncthreads();
  for (int st=128; st>0; st>>=1){ if (tid<st) red[tid]+=red[tid+st]; __syncthreads(); }
  float mean = red[0]*(1.f/512.f); __syncthreads();
  float d0=v0-mean, d1=v1-mean;
  red[tid]=d0*d0+d1*d1; __syncthreads();
  for (int st=128; st>0; st>>=1){ if (tid<st) red[tid]+=red[tid+st]; __syncthreads(); }
  float var = red[0]*(1.f/512.f);
  float rstd = rsqrtf(var+1e-5f);
  float a0 = d0*rstd*g[tid]+b[tid];
  float a1 = d1*rstd*g[tid+256]+b[tid+256];
  xn[s2*D+tid]=a0; xn[s2*D+tid+256]=a1;
  xnl[tid]=a0; xnl[tid+256]=a1;
  __syncthreads();
  int j = tid;
  float e = (float)(2*j)*(1.f/512.f);
  float inv = 1.f/powf(10000.f, e);
  float ang = (float)s2 * inv;
  float c = cosf(ang), sn = sinf(ang);
  float p0 = xnl[2*j], p1 = xnl[2*j+1];
  xr[s2*D+2*j]   = p0*c - p1*sn;
  xr[s2*D+2*j+1] = p1*c + p0*sn;
}

// K2: column means
__global__ void __launch_bounds__(256) k_colmean(const float* __restrict__ xr,
    const float* __restrict__ bank, float* __restrict__ meanxr, float* __restrict__ memmean){
  int tid=threadIdx.x;
  if (blockIdx.x<2){
    int d2 = blockIdx.x*256+tid; float acc=0.f;
    for (int s2=0;s2<S;++s2) acc += xr[s2*D+d2];
    meanxr[d2]=acc*(1.f/256.f);
  } else {
    int d2=(blockIdx.x-2)*256+tid; float acc=0.f;
    for (int r=0;r<512;++r) acc += bank[r*D+d2];
    memmean[d2]=acc*(1.f/512.f);
  }
}

// K3a: parallel fold GEMVs. 21 blocks x 32 outputs.
__global__ void __launch_bounds__(256) k_fold(const float* __restrict__ meanxr,
    const float* __restrict__ memmean,
    const float* __restrict__ mw1, const float* __restrict__ mb1,
    const float* __restrict__ iw1, const float* __restrict__ ib1,
    const float* __restrict__ sw1, const float* __restrict__ sb1,
    const float* __restrict__ ww1, const float* __restrict__ wb1,
    float* __restrict__ mempart, float* __restrict__ ctxint,
    float* __restrict__ ctxsel, float* __restrict__ gw){
  __shared__ float vec[512];
  __shared__ float red[256];
  int b=blockIdx.x, tid=threadIdx.x;
  int seg, obase; const float* W; const float* bias; float* outp; int N; int rowoff;
  if (b<16){ seg=0; obase=b*32; W=mw1; bias=mb1; outp=mempart; N=512; rowoff=512; }
  else if (b<18){ seg=1; obase=(b-16)*32; W=iw1; bias=ib1; outp=ctxint; N=64; rowoff=512; }
  else if (b<19){ seg=2; obase=0; W=sw1; bias=sb1; outp=ctxsel; N=32; rowoff=512; }
  else { seg=3; obase=(b-19)*32; W=ww1; bias=wb1; outp=gw; N=64; rowoff=0; }
  const float* v=(seg==0)?memmean:meanxr;
  vec[tid]=v[tid]; vec[tid+256]=v[tid+256];
  __syncthreads();
  int ol=tid&31, ch=tid>>5;
  float a=0.f;
  int d0=ch*64;
  for (int d=d0; d<d0+64; ++d) a=fmaf(vec[d], W[(size_t)(rowoff+d)*N+obase+ol], a);
  red[tid]=a; __syncthreads();
  if (tid<32){
    float s=bias[obase+tid];
    #pragma unroll
    for (int k=0;k<8;++k) s+=red[k*32+tid];
    if (seg==3) s=gelu_f(s);
    outp[obase+tid]=s;
  }
}

// K3b: window head -> kk
__global__ void k_kk(const float* __restrict__ gw, const float* __restrict__ ww2,
    const float* __restrict__ wb2, int* __restrict__ kkout){
  int tid=threadIdx.x;  // 64
  float a=gw[tid]*ww2[tid];
  #pragma unroll
  for (int m=32;m>0;m>>=1) a+=__shfl_xor(a,m,64);
  if (tid==0){
    float win=sigm_f(a+wb2[0])*3840.f+256.f;
    float asp=0.1f*(win*(1.f/4096.f));
    float t=262144.f*asp;
    int kk=(int)t; if (kk<1) kk=1;
    *kkout=kk;
  }
}

// K4: per-position selection MLP (softmax pw) + intensity. 2-way K-split dots.
__global__ void __launch_bounds__(256) k_selint(const float* __restrict__ xr,
    const float* __restrict__ ctxsel, const float* __restrict__ ctxint,
    const float* __restrict__ sw1, const float* __restrict__ sw2, const float* __restrict__ sb2,
    const float* __restrict__ iw1, const float* __restrict__ iw2, const float* __restrict__ ib2,
    float* __restrict__ pw, float* __restrict__ inten){
  int s2=blockIdx.x, tid=threadIdx.x;
  __shared__ float xl[512]; __shared__ float red[192];
  __shared__ float h1[32], h2[64], lg[16];
  xl[tid]=xr[s2*D+tid]; xl[tid+256]=xr[s2*D+tid+256];
  __syncthreads();
  if (tid<192){
    int half=(tid>=96)?1:0; int o=tid-96*half;
    int d0=half<<8;
    float a=0.f;
    if (o<32){
      const float* Wp=sw1+o;
      #pragma unroll 4
      for (int d=d0; d<d0+256; ++d) a=fmaf(xl[d], Wp[d*32], a);
    } else {
      const float* Wp=iw1+(o-32);
      #pragma unroll 4
      for (int d=d0; d<d0+256; ++d) a=fmaf(xl[d], Wp[d*64], a);
    }
    red[tid]=a;
  }
  __syncthreads();
  if (tid<96){
    float a=red[tid]+red[tid+96];
    if (tid<32) h1[tid]=gelu_f(a+ctxsel[tid]);
    else h2[tid-32]=gelu_f(a+ctxint[tid-32]);
  }
  __syncthreads();
  if (tid<16){ float a=sb2[tid]; for (int h=0;h<32;++h) a=fmaf(h1[h], sw2[h*16+tid], a); lg[tid]=a; }
  __syncthreads();
  if (tid==0){
    float m=lg[0]; for (int p2=1;p2<16;++p2) m=fmaxf(m,lg[p2]);
    float sm=0.f; float e[16];
    for (int p2=0;p2<16;++p2){ e[p2]=expf(lg[p2]-m); sm+=e[p2]; }
    float r=1.f/sm;
    for (int p2=0;p2<16;++p2) pw[s2*16+p2]=e[p2]*r;
  }
  if (tid==64){ float a=ib2[0]; for (int h=0;h<64;++h) a=fmaf(h2[h], iw2[h], a); inten[s2]=sigm_f(a); }
}

// K5a: shared-sweep histogram. grid (32 pos-groups, 8 chunks); 8 pos/block.
__global__ __launch_bounds__(1024) __attribute__((amdgpu_waves_per_eu(4,4)))
void k_fhist(const float* __restrict__ pat,
    const float* __restrict__ pw, unsigned* __restrict__ ghist){
  __shared__ unsigned hist[4*8192];   // 128KB
  __shared__ float pws8[128];
  int g=blockIdx.x, c=blockIdx.y, tid=threadIdx.x;
  if (tid<128) pws8[tid]=pw[g*128+tid];
  for (int i=tid;i<32768;i+=1024) hist[i]=0u;
  __syncthreads();
  const float4* patv=(const float4*)pat;
  for (int it=0;it<8;++it){
    int f4=(c<<13)+(it<<10)+tid;
    float4 acc[8];
    #pragma unroll
    for (int pp=0;pp<8;++pp) acc[pp]=make_float4(0.f,0.f,0.f,0.f);
    #pragma unroll 4
    for (int p=0;p<16;++p){
      float4 pv=patv[(p<<16)+f4];
      #pragma unroll
      for (int pp=0;pp<8;++pp){
        float w=pws8[(pp<<4)+p];
        acc[pp].x=fmaf(w,pv.x,acc[pp].x); acc[pp].y=fmaf(w,pv.y,acc[pp].y);
        acc[pp].z=fmaf(w,pv.z,acc[pp].z); acc[pp].w=fmaf(w,pv.w,acc[pp].w);
      }
    }
    #pragma unroll
    for (int pp=0;pp<8;++pp){
      unsigned add=(pp&1)?0x10000u:1u;
      unsigned* h=&hist[(pp>>1)<<13];
      atomicAdd(&h[(__float_as_uint(acc[pp].x)&0x7fffffffu)>>18],add);
      atomicAdd(&h[(__float_as_uint(acc[pp].y)&0x7fffffffu)>>18],add);
      atomicAdd(&h[(__float_as_uint(acc[pp].z)&0x7fffffffu)>>18],add);
      atomicAdd(&h[(__float_as_uint(acc[pp].w)&0x7fffffffu)>>18],add);
    }
  }
  __syncthreads();
  for (int i=tid;i<32768;i+=1024){
    unsigned v=hist[i];
    if (v){
      int pair=i>>13, bin=i&8191;
      int pos0=(g<<3)+(pair<<1);
      unsigned lo=v&0xffffu, hi=v>>16;
      if (lo) atomicAdd(&ghist[(pos0<<13)+bin], lo);
      if (hi) atomicAdd(&ghist[((pos0+1)<<13)+bin], hi);
    }
  }
}

// K5b: per-position threshold bin from 8192-bin global histogram.
__global__ void __launch_bounds__(256) k_fth(const unsigned* __restrict__ ghist,
    const int* __restrict__ kkin, unsigned* __restrict__ meta){
  int pos=blockIdx.x, tid=threadIdx.x;
  __shared__ unsigned part[256]; __shared__ unsigned sup[16];
  const unsigned* h=ghist+(pos<<13);
  unsigned s=0;
  for (int k=0;k<32;++k) s+=h[tid*32+k];
  part[tid]=s; __syncthreads();
  if (tid<16){ unsigned t=0; for (int k=0;k<16;++k) t+=part[tid*16+k]; sup[tid]=t; }
  __syncthreads();
  if (tid==0){
    unsigned kk=(unsigned)(*kkin);
    unsigned cum=0; int u=0;
    for (int j=15;j>=0;--j){ if (cum+sup[j]>=kk){ u=j; break; } cum+=sup[j]; }
    int t=u*16;
    for (int j=u*16+15;j>=u*16;--j){ if (cum+part[j]>=kk){ t=j; break; } cum+=part[j]; }
    int b=t*32;
    for (int j=t*32+31;j>=t*32;--j){ if (cum+h[j]>=kk){ b=j; break; } cum+=h[j]; }
    meta[pos*4+0]=(unsigned)b; meta[pos*4+1]=kk-cum; meta[pos*4+2]=h[b];
  }
}

// K5c: shared-sweep masked matvec. grid (32 pos-groups, 8 chunks); 8 pos/block.
__global__ __launch_bounds__(1024) __attribute__((amdgpu_waves_per_eu(4,4)))
void k_fmv(const float* __restrict__ pat,
    const float* __restrict__ pw, const float* __restrict__ xn,
    const unsigned* __restrict__ meta, float* __restrict__ goutr, float* __restrict__ goutrb,
    unsigned* __restrict__ gbits, float* __restrict__ gcon,
    unsigned short* __restrict__ grow, unsigned* __restrict__ gcount, unsigned* __restrict__ gofl){
  __shared__ float pws8[128];
  __shared__ float xnl[4096];
  __shared__ float outr[512];
  __shared__ float outrb[512];
  __shared__ unsigned lcnt[8];
  int g=blockIdx.x, c=blockIdx.y, tid=threadIdx.x;
  if (tid<128) pws8[tid]=pw[g*128+tid];
  for (int i=tid;i<4096;i+=1024) xnl[i]=xn[(g<<12)+i];
  if (tid<512){ outr[tid]=0.f; outrb[tid]=0.f; }
  if (tid<8) lcnt[tid]=0u;
  __syncthreads();
  unsigned bst[8];
  #pragma unroll
  for (int pp=0;pp<8;++pp) bst[pp]=meta[((g<<3)+pp)*4];
  const float4* patv=(const float4*)pat;
  int lane=tid&63;
  for (int it=0;it<8;++it){
    int f4=(c<<13)+(it<<10)+tid;
    int rowg=f4>>7;
    int row=rowg&63;
    int col0=(f4&127)<<2;
    float4 acc[8];
    #pragma unroll
    for (int pp=0;pp<8;++pp) acc[pp]=make_float4(0.f,0.f,0.f,0.f);
    #pragma unroll 4
    for (int p=0;p<16;++p){
      float4 pv=patv[(p<<16)+f4];
      #pragma unroll
      for (int pp=0;pp<8;++pp){
        float w=pws8[(pp<<4)+p];
        acc[pp].x=fmaf(w,pv.x,acc[pp].x); acc[pp].y=fmaf(w,pv.y,acc[pp].y);
        acc[pp].z=fmaf(w,pv.z,acc[pp].z); acc[pp].w=fmaf(w,pv.w,acc[pp].w);
      }
    }
    #pragma unroll
    for (int pp=0;pp<8;++pp){
      float4 xq=*(const float4*)&xnl[(pp<<9)+col0];
      float vv[4]={acc[pp].x,acc[pp].y,acc[pp].z,acc[pp].w};
      float xv[4]={xq.x,xq.y,xq.z,xq.w};
      float lacc=0.f;
      #pragma unroll
      for (int q=0;q<4;++q){
        unsigned bits=__float_as_uint(vv[q])&0x7fffffffu;
        unsigned pfx=bits>>18;
        if (pfx>bst[pp]) lacc=fmaf(vv[q],xv[q],lacc);
        else if (pfx==bst[pp]){
          float con=vv[q]*xv[q];
          atomicAdd(&outrb[(pp<<6)+row], con);
          unsigned idx=atomicAdd(&lcnt[pp],1u);
          if (idx<CCAP){
            int o=((((g<<3)+pp)<<3)+c)*CCAP+idx;
            gbits[o]=bits; gcon[o]=con; grow[o]=(unsigned short)rowg;
          }
        }
      }
      #pragma unroll
      for (int m=32;m>0;m>>=1) lacc+=__shfl_xor(lacc,m,64);
      if (lane==0 && lacc!=0.f) atomicAdd(&outr[(pp<<6)+row], lacc);
    }
  }
  __syncthreads();
  if (tid<512){
    int pp=tid>>6, r=tid&63;
    goutr [((g<<3)+pp)*512+(c<<6)+r]=outr[tid];
    goutrb[((g<<3)+pp)*512+(c<<6)+r]=outrb[tid];
  }
  if (tid<8){
    unsigned n=lcnt[tid];
    gcount[((g<<3)+tid)*8+c]=n;
    if (n>CCAP) gofl[(g<<3)+tid]=1u;
  }
}

// K5d: per-position exact refinement over stashed candidates + apply + residual + LN2.
__global__ void __launch_bounds__(256) k_fref(const float* __restrict__ x,
    const float* __restrict__ goutr, const float* __restrict__ goutrb,
    const unsigned* __restrict__ meta, const unsigned* __restrict__ gcount,
    const unsigned* __restrict__ gofl, const unsigned* __restrict__ gbits,
    const float* __restrict__ gcon, const unsigned short* __restrict__ grow,
    const float* __restrict__ inten, const float* __restrict__ n2g, const float* __restrict__ n2b,
    float* __restrict__ co){
  int pos=blockIdx.x, tid=threadIdx.x;
  __shared__ float outr[512]; __shared__ unsigned rhist[2048]; __shared__ unsigned rpart[128];
  __shared__ unsigned thsh[4]; __shared__ float red[256];
  outr[tid]=goutr[pos*512+tid]; outr[tid+256]=goutr[pos*512+tid+256];
  unsigned bstar=meta[pos*4], rnk=meta[pos*4+1];
  bool ofl = gofl[pos]!=0u;
  if (ofl){
    outr[tid]+=goutrb[pos*512+tid]; outr[tid+256]+=goutrb[pos*512+tid+256];
    __syncthreads();
  } else {
    for (int i=tid;i<2048;i+=256) rhist[i]=0u;
    __syncthreads();
    for (int c=0;c<8;++c){
      unsigned n=gcount[pos*8+c]; if (n>CCAP) n=CCAP;
      const unsigned* cb=gbits+(((pos<<3)+c)*CCAP);
      for (unsigned i=tid;i<n;i+=256) atomicAdd(&rhist[(cb[i]>>7)&0x7ffu],1u);
    }
    __syncthreads();
    if (tid<128){ unsigned t=0;
      #pragma unroll
      for (int k=0;k<16;++k) t+=rhist[tid*16+k];
      rpart[tid]=t; }
    __syncthreads();
    if (tid==0){
      unsigned cum=0; int rp=0;
      for (int j=127;j>=0;--j){ if (cum+rpart[j]>=rnk){ rp=j; break; } cum+=rpart[j]; }
      int sub=rp*16;
      for (int j=rp*16+15;j>=rp*16;--j){ if (cum+rhist[j]>=rnk){ sub=j; break; } cum+=rhist[j]; }
      thsh[0]=(unsigned)sub; thsh[1]=rnk-cum;
    }
    __syncthreads();
    unsigned sub=thsh[0], r2=thsh[1];
    if (tid<128) rhist[tid]=0u;
    __syncthreads();
    for (int c=0;c<8;++c){
      unsigned n=gcount[pos*8+c]; if (n>CCAP) n=CCAP;
      const unsigned* cb=gbits+(((pos<<3)+c)*CCAP);
      for (unsigned i=tid;i<n;i+=256) if (((cb[i]>>7)&0x7ffu)==sub) atomicAdd(&rhist[cb[i]&127u],1u);
    }
    __syncthreads();
    if (tid==0){
      unsigned cum=0; unsigned lo=0;
      for (int j=127;j>=0;--j){ if (cum+rhist[j]>=r2){ lo=(unsigned)j; break; } cum+=rhist[j]; }
      thsh[2]=(bstar<<18)|(sub<<7)|lo;
    }
    __syncthreads();
    unsigned thb=thsh[2];
    for (int c=0;c<8;++c){
      unsigned n=gcount[pos*8+c]; if (n>CCAP) n=CCAP;
      int base=((pos<<3)+c)*CCAP;
      for (unsigned i=tid;i<n;i+=256)
        if (gbits[base+i]>=thb) atomicAdd(&outr[grow[base+i]], gcon[base+i]);
    }
  }
  __syncthreads();
  float it=inten[pos];
  float t0=x[pos*D+tid]+outr[tid]*it;
  float t1=x[pos*D+tid+256]+outr[tid+256]*it;
  red[tid]=t0+t1; __syncthreads();
  for (int st=128;st>0;st>>=1){ if (tid<st) red[tid]+=red[tid+st]; __syncthreads(); }
  float mean=red[0]*(1.f/512.f); __syncthreads();
  float d0=t0-mean, d1=t1-mean;
  red[tid]=d0*d0+d1*d1; __syncthreads();
  for (int st=128;st>0;st>>=1){ if (tid<st) red[tid]+=red[tid+st]; __syncthreads(); }
  float var=red[0]*(1.f/512.f);
  float rstd=rsqrtf(var+1e-5f);
  co[pos*D+tid]=d0*rstd*n2g[tid]+n2b[tid];
  co[pos*D+tid+256]=d1*rstd*n2g[tid+256]+n2b[tid+256];
}

// ---------------- split-K GEMM: 32x64 tile, partials via atomicAdd ----------------
// AMODE: 0 plain A, 1 silu(A), 2 gated-A (silu(g)*v from [*,4096] ff layout)
template<int AMODE, int RES, int KS>
__global__ void __launch_bounds__(256) k_gemmsk(const float* __restrict__ A, const float* __restrict__ W,
    const float* __restrict__ bias, const float* __restrict__ res,
    float* __restrict__ C, int K, int N){
  __shared__ float Ast[32][36];
  __shared__ float Ws[32][68];
  int tid=threadIdx.x;
  int cb=blockIdx.x<<6;
  int s0=blockIdx.y<<5;
  int kz=blockIdx.z;
  int Kslice=K/KS, kbase=kz*Kslice;
  int rid=tid>>5, cid=tid&31;
  int arow=tid>>3, akq=tid&7;
  int wrow=tid>>4, wc4=tid&15;
  float acc[4][2]={{0.f,0.f},{0.f,0.f},{0.f,0.f},{0.f,0.f}};
  const int LDA = (AMODE==2) ? 4096 : K;
  const float* Aptr = A + (size_t)(s0+arow)*LDA + kbase + (akq<<2);
  const float* Wptr0 = W + (size_t)(kbase+wrow)*N + cb + (wc4<<2);
  const float* Wptr1 = W + (size_t)(kbase+wrow+16)*N + cb + (wc4<<2);
  float4 av;
  if (AMODE==2) av=gate4(Aptr); else if (AMODE==1) av=silu4(Aptr); else av=*(const float4*)Aptr;
  float4 w0=*(const float4*)Wptr0;
  float4 w1=*(const float4*)Wptr1;
  for (int k0=0;k0<Kslice;k0+=32){
    Ast[(akq<<2)+0][arow]=av.x; Ast[(akq<<2)+1][arow]=av.y;
    Ast[(akq<<2)+2][arow]=av.z; Ast[(akq<<2)+3][arow]=av.w;
    *(float4*)&Ws[wrow][wc4<<2]=w0;
    *(float4*)&Ws[wrow+16][wc4<<2]=w1;
    __syncthreads();
    if (k0+32<Kslice){
      if (AMODE==2) av=gate4(Aptr+k0+32);
      else if (AMODE==1) av=silu4(Aptr+k0+32);
      else av=*(const float4*)(Aptr+k0+32);
      w0=*(const float4*)(Wptr0 + (size_t)(k0+32)*N);
      w1=*(const float4*)(Wptr1 + (size_t)(k0+32)*N);
    }
    #pragma unroll
    for (int kk=0;kk<32;++kk){
      float4 a4=*(const float4*)&Ast[kk][rid<<2];
      float b0=Ws[kk][cid], b1=Ws[kk][cid+32];
      acc[0][0]=fmaf(a4.x,b0,acc[0][0]); acc[0][1]=fmaf(a4.x,b1,acc[0][1]);
      acc[1][0]=fmaf(a4.y,b0,acc[1][0]); acc[1][1]=fmaf(a4.y,b1,acc[1][1]);
      acc[2][0]=fmaf(a4.z,b0,acc[2][0]); acc[2][1]=fmaf(a4.z,b1,acc[2][1]);
      acc[3][0]=fmaf(a4.w,b0,acc[3][0]); acc[3][1]=fmaf(a4.w,b1,acc[3][1]);
    }
    __syncthreads();
  }
  float bb0=(kz==0)?bias[cb+cid]:0.f;
  float bb1=(kz==0)?bias[cb+cid+32]:0.f;
  #pragma unroll
  for (int r=0;r<4;++r){
    int row=s0+(rid<<2)+r;
    #pragma unroll
    for (int c=0;c<2;++c){
      int col=cb+cid+(c<<5);
      float v=acc[r][c]+(c?bb1:bb0);
      if (RES && kz==0) v+=res[(size_t)row*N+col];
      atomicAdd(&C[(size_t)row*N+col], v);
    }
  }
}

// ---------------- GEMM64: 64x64 tile, 4x4 per thread ----------------
template<int ACT, int RES>
__global__ void __launch_bounds__(256) k_gemm64(const float* __restrict__ A, const float* __restrict__ W,
    const float* __restrict__ bias, const float* __restrict__ res,
    float* __restrict__ C, int K, int N){
  __shared__ float Ast[32][68];
  __shared__ float Ws[32][68];
  int tid=threadIdx.x;
  int cb=blockIdx.x<<6;
  int s0=blockIdx.y<<6;
  int rid=tid>>4, cid=tid&15;
  int ar=tid>>3, akq=tid&7;
  int wrow=tid>>4, wc4=tid&15;
  float acc[4][4];
  #pragma unroll
  for (int i=0;i<4;++i){
    #pragma unroll
    for (int j=0;j<4;++j) acc[i][j]=0.f;
  }
  const float* Ap0 = A + (size_t)(s0+ar)*K + (akq<<2);
  const float* Ap1 = A + (size_t)(s0+ar+32)*K + (akq<<2);
  const float* Wp0 = W + (size_t)wrow*N + cb + (wc4<<2);
  const float* Wp1 = W + (size_t)(wrow+16)*N + cb + (wc4<<2);
  float4 a0=*(const float4*)Ap0, a1=*(const float4*)Ap1;
  float4 w0=*(const float4*)Wp0, w1=*(const float4*)Wp1;
  for (int k0=0;k0<K;k0+=32){
    Ast[(akq<<2)+0][ar]=a0.x; Ast[(akq<<2)+1][ar]=a0.y;
    Ast[(akq<<2)+2][ar]=a0.z; Ast[(akq<<2)+3][ar]=a0.w;
    Ast[(akq<<2)+0][ar+32]=a1.x; Ast[(akq<<2)+1][ar+32]=a1.y;
    Ast[(akq<<2)+2][ar+32]=a1.z; Ast[(akq<<2)+3][ar+32]=a1.w;
    *(float4*)&Ws[wrow][wc4<<2]=w0;
    *(float4*)&Ws[wrow+16][wc4<<2]=w1;
    __syncthreads();
    if (k0+32<K){
      a0=*(const float4*)(Ap0+k0+32);
      a1=*(const float4*)(Ap1+k0+32);
      w0=*(const float4*)(Wp0 + (size_t)(k0+32)*N);
      w1=*(const float4*)(Wp1 + (size_t)(k0+32)*N);
    }
    #pragma unroll
    for (int kk=0;kk<32;++kk){
      float4 a4=*(const float4*)&Ast[kk][rid<<2];
      float b0=Ws[kk][cid], b1=Ws[kk][cid+16], b2=Ws[kk][cid+32], b3=Ws[kk][cid+48];
      acc[0][0]=fmaf(a4.x,b0,acc[0][0]); acc[0][1]=fmaf(a4.x,b1,acc[0][1]); acc[0][2]=fmaf(a4.x,b2,acc[0][2]); acc[0][3]=fmaf(a4.x,b3,acc[0][3]);
      acc[1][0]=fmaf(a4.y,b0,acc[1][0]); acc[1][1]=fmaf(a4.y,b1,acc[1][1]); acc[1][2]=fmaf(a4.y,b2,acc[1][2]); acc[1][3]=fmaf(a4.y,b3,acc[1][3]);
      acc[2][0]=fmaf(a4.z,b0,acc[2][0]); acc[2][1]=fmaf(a4.z,b1,acc[2][1]); acc[2][2]=fmaf(a4.z,b2,acc[2][2]); acc[2][3]=fmaf(a4.z,b3,acc[2][3]);
      acc[3][0]=fmaf(a4.w,b0,acc[3][0]); acc[3][1]=fmaf(a4.w,b1,acc[3][1]); acc[3][2]=fmaf(a4.w,b2,acc[3][2]); acc[3][3]=fmaf(a4.w,b3,acc[3][3]);
    }
    __syncthreads();
  }
  #pragma unroll
  for (int i=0;i<4;++i){
    int row=s0+(rid<<2)+i;
    #pragma unroll
    for (int j=0;j<4;++j){
      int col=cb+cid+(j<<4);
      float v=acc[i][j]+bias[col];
      if (ACT==1) v=gelu_f(v);
      if (ACT==2) v=silu_f(v);
      if (RES) v+=res[(size_t)row*N+col];
      C[(size_t)row*N+col]=v;
    }
  }
}

extern "C" void kernel_launch(void* const* d_in, const int* in_sizes, int n_in,
                              void* d_out, int out_size, void* d_ws, size_t ws_size,
                              hipStream_t stream){
  const float* x   =(const float*)d_in[0];
  const float* pat =(const float*)d_in[1];
  const float* sw1 =(const float*)d_in[2];
  const float* sb1 =(const float*)d_in[3];
  const float* sw2 =(const float*)d_in[4];
  const float* sb2 =(const float*)d_in[5];
  const float* ww1 =(const float*)d_in[6];
  const float* wb1 =(const float*)d_in[7];
  const float* ww2 =(const float*)d_in[8];
  const float* wb2 =(const float*)d_in[9];
  const float* iw1 =(const float*)d_in[10];
  const float* ib1 =(const float*)d_in[11];
  const float* iw2 =(const float*)d_in[12];
  const float* ib2 =(const float*)d_in[13];
  const float* mw1 =(const float*)d_in[14];
  const float* mb1 =(const float*)d_in[15];
  const float* mw2 =(const float*)d_in[16];
  const float* mb2 =(const float*)d_in[17];
  const float* bank=(const float*)d_in[18];
  const float* upw =(const float*)d_in[19];
  const float* upb =(const float*)d_in[20];
  const float* dww =(const float*)d_in[21];
  const float* dwb =(const float*)d_in[22];
  const float* n1g =(const float*)d_in[23];
  const float* n1b =(const float*)d_in[24];
  const float* n2g =(const float*)d_in[25];
  const float* n2b =(const float*)d_in[26];
  float* out=(float*)d_out;

  float* w = (float*)d_ws;
  float* xn     = w;                 // 131072
  float* xr     = xn+131072;         // 131072
  float* meanxr = xr+131072;         // 512
  float* memmean= meanxr+512;        // 512
  float* pwb    = memmean+512;       // 4096
  float* inten  = pwb+4096;          // 256
  float* ctxsel = inten+256;         // 32
  float* ctxint = ctxsel+32;         // 64
  float* mempart= ctxint+64;         // 512
  float* gwb    = mempart+512;       // 64
  float* co     = gwb+64;            // 131072
  float* h1     = co+131072;         // 131072 (zeroed: split-K target)
  float* co2    = h1+131072;         // 131072 (zeroed: split-K target)
  float* ff     = co2+131072;        // 1048576
  float* gv     = ff+1048576;        // 524288 (unused, kept for layout)
  int*   kkp    = (int*)(gv+524288);          // 4
  unsigned* meta= (unsigned*)(kkp+4);         // 1024
  unsigned* ghist = (unsigned*)(meta+1024);   // 2097152 u32 (zeroed)
  unsigned* gofl  = ghist+2097152;            // 256 (zeroed)
  float* goutr  = (float*)(gofl+256);         // 131072 f32
  float* goutrb = goutr+131072;               // 131072 f32
  unsigned* gcount=(unsigned*)(goutrb+131072);// 2048
  unsigned* gbits = gcount+2048;              // 2097152 u32
  float* gcon   = (float*)(gbits+2097152);    // 2097152 f32
  unsigned short* grow = (unsigned short*)(gcon+2097152); // 2097152 u16

  hipMemsetAsync(ghist, 0, (size_t)(2097152+256)*4, stream);
  hipMemsetAsync(h1, 0, (size_t)2*131072*4, stream);       // h1 + co2
  hipMemsetAsync(out, 0, (size_t)out_size*4, stream);

  k_ln_rope<<<S,256,0,stream>>>(x,n1g,n1b,xn,xr);
  k_colmean<<<4,256,0,stream>>>(xr,bank,meanxr,memmean);
  k_fold<<<21,256,0,stream>>>(meanxr,memmean,mw1,mb1,iw1,ib1,sw1,sb1,ww1,wb1,
                              mempart,ctxint,ctxsel,gwb);
  k_kk<<<1,64,0,stream>>>(gwb,ww2,wb2,kkp);
  k_selint<<<S,256,0,stream>>>(xr,ctxsel,ctxint,sw1,sw2,sb2,iw1,iw2,ib2,pwb,inten);
  k_fhist<<<dim3(32,8),1024,0,stream>>>(pat,pwb,ghist);
  k_fth<<<S,256,0,stream>>>(ghist,kkp,(unsigned*)meta);
  k_fmv<<<dim3(32,8),1024,0,stream>>>(pat,pwb,xn,(unsigned*)meta,goutr,goutrb,gbits,gcon,grow,gcount,gofl);
  k_fref<<<S,256,0,stream>>>(x,goutr,goutrb,(unsigned*)meta,gcount,gofl,gbits,gcon,grow,inten,n2g,n2b,co);
  // mem-MLP: h1raw = co@mw1 + mempart  (silu applied at next A-load)
  k_gemmsk<0,0,4><<<dim3(8,8,4),256,0,stream>>>(co, mw1, mempart, nullptr, h1, 512, 512);
  // co2 = silu(h1raw)@mw2 + mb2 + co
  k_gemmsk<1,1,4><<<dim3(8,8,4),256,0,stream>>>(h1, mw2, mb2, co, co2, 512, 512);
  // ff = co2@upw + upb
  k_gemm64<0,0><<<dim3(64,4),256,0,stream>>>(co2, upw, upb, nullptr, ff, 512, 4096);
  // out = gate(ff)@dww + dwb + co2
  k_gemmsk<2,1,8><<<dim3(8,8,8),256,0,stream>>>(ff, dww, dwb, co2, out, 2048, 512);
}